// Round 4
// baseline (6492.353 us; speedup 1.0000x reference)
//
#include <hip/hip_runtime.h>
#include <math.h>

#define THREADS 256
constexpr int BATCH = 16;

// ---------------------------------------------------------------------------
// Workspace layout (floats):
//   K0t [125][23]        : 2875      K1t [20][125][23] : 57500
//   K2t [20][125][20]    : 50000
//   A0  [16][20][33^3]   : 11,499,840   (P2 aliases this region after combine)
//   A1  [16][20][18^3]   : 1,866,240
//   P1  [G1][16][23][18^3]  (tier A: G1=5 -> 10,730,880 fl; total 96.8 MB)
// ---------------------------------------------------------------------------

__global__ void synth_kernel(const float* __restrict__ W0,
                             const float* __restrict__ W1,
                             const float* __restrict__ W2,
                             float* __restrict__ K0,
                             float* __restrict__ K1,
                             float* __restrict__ K2) {
  __shared__ float Bsh[3][128];
  __shared__ float nrm[3];
  const int t = threadIdx.x;
  if (t < 125) {
    float dz = (float)(t / 25) - 2.0f;
    float dy = (float)((t / 5) % 5) - 2.0f;
    float dx = (float)(t % 5) - 2.0f;
    float r = sqrtf(dx * dx + dy * dy + dz * dz);
    for (int j = 0; j < 3; ++j) {
      float d = (r - (float)j) * (1.0f / 0.6f);
      Bsh[j][t] = expf(-0.5f * d * d);
    }
  }
  __syncthreads();
  if (t < 3) {
    float s = 0.f;
    for (int k = 0; k < 125; ++k) s += Bsh[t][k] * Bsh[t][k];
    nrm[t] = rsqrtf(s);
  }
  __syncthreads();
  if (t < 125) {
    for (int j = 0; j < 3; ++j) Bsh[j][t] *= nrm[j];
  }
  __syncthreads();
  for (int i = t; i < 125 * 23; i += blockDim.x) {
    int k = i / 23, oc = i % 23;
    const float* w = W0 + oc * 3;
    K0[i] = w[0] * Bsh[0][k] + w[1] * Bsh[1][k] + w[2] * Bsh[2][k];
  }
  for (int i = t; i < 20 * 125 * 23; i += blockDim.x) {
    int oc = i % 23, k = (i / 23) % 125, ic = i / (23 * 125);
    const float* w = W1 + (oc * 20 + ic) * 3;
    K1[i] = w[0] * Bsh[0][k] + w[1] * Bsh[1][k] + w[2] * Bsh[2][k];
  }
  for (int i = t; i < 20 * 125 * 20; i += blockDim.x) {
    int oc = i % 20, k = (i / 20) % 125, ic = i / (20 * 125);
    const float* w = W2 + (oc * 20 + ic) * 3;
    K2[i] = w[0] * Bsh[0][k] + w[1] * Bsh[1][k] + w[2] * Bsh[2][k];
  }
}

// Direct conv, stride 2, pad 3, 5^3 taps. Each thread computes an NX-strip of
// x-consecutive output voxels for ALL OC channels of one ic-group. Weights for
// the current input channel staged in LDS (padded to OCP, zero-filled), read as
// broadcast float4 — each read feeds 4*NX FMAs. NX=2 keeps acc at 46 VGPRs;
// __launch_bounds__(...,4) caps allocation at 128 VGPR (round-3 spilled at 256).
// EPI: 0 = partials [g][b][OC][vox], 1 = gated (G==1, OC==23), 2 = plain (G==1).
template <int ICTOT, int ICG, int OC, int DIN, int DOUT, int NX, int EPI>
__global__ __launch_bounds__(THREADS, 4)
void conv_kernel(const float* __restrict__ in, const float* __restrict__ K,
                 float* __restrict__ out) {
  constexpr int NVOX = DOUT * DOUT * DOUT;
  constexpr int G = ICTOT / ICG;
  constexpr int DIN3 = DIN * DIN * DIN;
  constexpr int XS = (DOUT + NX - 1) / NX;   // strips per x-row
  constexpr int SPI = DOUT * DOUT * XS;      // strips per (b,g)
  constexpr int NB = (SPI + THREADS - 1) / THREADS;
  constexpr int OCP = (OC + 3) & ~3;
  constexpr int NV = 2 * NX + 3;

  __shared__ __align__(16) float wsh[125 * OCP];

  const int bid = blockIdx.x;
  const int chunk = bid % NB;
  const int gb = bid / NB;
  const int g = gb % G;
  const int b = gb / G;
  const int t = threadIdx.x;
  const int s = chunk * THREADS + t;
  const bool active = s < SPI;
  const int si = active ? s : 0;
  const int zo = si / (DOUT * XS);
  const int yo = (si / XS) % DOUT;
  const int xo0 = (si % XS) * NX;

  float acc[OC][NX];
#pragma unroll
  for (int oc = 0; oc < OC; ++oc)
#pragma unroll
    for (int n = 0; n < NX; ++n) acc[oc][n] = 0.f;

  const float* __restrict__ ip0 = in + (size_t)(b * ICTOT + g * ICG) * DIN3;
  const float* __restrict__ wp0 = K + (size_t)(g * ICG) * 125 * OC;

  int xic[NV];
  bool xok[NV];
#pragma unroll
  for (int p = 0; p < NV; ++p) {
    int xi = 2 * xo0 - 3 + p;
    xok[p] = (unsigned)xi < (unsigned)DIN;
    xic[p] = min(max(xi, 0), DIN - 1);
  }

  for (int icl = 0; icl < ICG; ++icl) {
    __syncthreads();
    for (int i = t; i < 125 * OCP; i += THREADS) {
      const int tap = i / OCP, oc = i % OCP;
      wsh[i] = (oc < OC) ? wp0[icl * 125 * OC + tap * OC + oc] : 0.f;
    }
    __syncthreads();
    const float* __restrict__ ipc = ip0 + (size_t)icl * DIN3;
    for (int kz = 0; kz < 5; ++kz) {
      const int zi = 2 * zo - 3 + kz;
      const bool zok = (unsigned)zi < (unsigned)DIN;
      const int zic = min(max(zi, 0), DIN - 1);
      for (int ky = 0; ky < 5; ++ky) {
        const int yi = 2 * yo - 3 + ky;
        const bool yzok = zok && ((unsigned)yi < (unsigned)DIN);
        const int yic = min(max(yi, 0), DIN - 1);
        const float* __restrict__ row = ipc + ((size_t)zic * DIN + yic) * DIN;
        float v[NV];
#pragma unroll
        for (int p = 0; p < NV; ++p) {
          const float val = row[xic[p]];
          v[p] = (yzok && xok[p]) ? val : 0.f;
        }
        const int kb = ((kz * 5 + ky) * 5) * OCP;
#pragma unroll
        for (int kx = 0; kx < 5; ++kx) {
#pragma unroll
          for (int c4 = 0; c4 < OCP / 4; ++c4) {
            const float4 w4 = *(const float4*)&wsh[kb + kx * OCP + 4 * c4];
#pragma unroll
            for (int j = 0; j < 4; ++j) {
              const int oc = c4 * 4 + j;
              if (oc < OC) {
                const float wj = (j == 0) ? w4.x : (j == 1) ? w4.y : (j == 2) ? w4.z : w4.w;
#pragma unroll
                for (int n = 0; n < NX; ++n)
                  acc[oc][n] = fmaf(wj, v[2 * n + kx], acc[oc][n]);
              }
            }
          }
        }
      }
    }
  }

  if (!active) return;
  const int vbase = (zo * DOUT + yo) * DOUT + xo0;

  if constexpr (EPI == 1) {
    float* __restrict__ op = out + (size_t)b * 20 * NVOX + vbase;
#pragma unroll
    for (int n = 0; n < NX; ++n) {
      if (xo0 + n < DOUT) {
        const float g0 = 1.f / (1.f + expf(-acc[20][n]));
        const float g1 = 1.f / (1.f + expf(-acc[21][n]));
        const float g2 = 1.f / (1.f + expf(-acc[22][n]));
#pragma unroll
        for (int c = 0; c < 5; ++c) op[(size_t)c * NVOX + n] = fmaxf(acc[c][n], 0.f);
#pragma unroll
        for (int c = 0; c < 3; ++c) op[(size_t)(5 + c) * NVOX + n] = acc[5 + c][n] * g0;
#pragma unroll
        for (int c = 0; c < 5; ++c) op[(size_t)(8 + c) * NVOX + n] = acc[8 + c][n] * g1;
#pragma unroll
        for (int c = 0; c < 7; ++c) op[(size_t)(13 + c) * NVOX + n] = acc[13 + c][n] * g2;
      }
    }
  } else if constexpr (EPI == 0) {
    float* __restrict__ op = out + ((size_t)(g * BATCH + b) * OC) * NVOX + vbase;
#pragma unroll
    for (int oc = 0; oc < OC; ++oc)
#pragma unroll
      for (int n = 0; n < NX; ++n)
        if (xo0 + n < DOUT) op[(size_t)oc * NVOX + n] = acc[oc][n];
  } else {
    float* __restrict__ op = out + (size_t)b * OC * NVOX + vbase;
#pragma unroll
    for (int oc = 0; oc < OC; ++oc)
#pragma unroll
      for (int n = 0; n < NX; ++n)
        if (xo0 + n < DOUT) op[(size_t)oc * NVOX + n] = acc[oc][n];
  }
}

// Sum ic-group partials (23 ch) + gating -> 20 ch output.
template <int G, int NVOX>
__global__ __launch_bounds__(THREADS)
void combine_gate_kernel(const float* __restrict__ P, float* __restrict__ out) {
  const int tid = blockIdx.x * THREADS + threadIdx.x;
  if (tid >= BATCH * NVOX) return;
  const int vox = tid % NVOX;
  const int b = tid / NVOX;
  float s[23];
#pragma unroll
  for (int oc = 0; oc < 23; ++oc) s[oc] = 0.f;
  for (int g = 0; g < G; ++g) {
    const float* __restrict__ p = P + ((size_t)(g * BATCH + b) * 23) * NVOX + vox;
#pragma unroll
    for (int oc = 0; oc < 23; ++oc) s[oc] += p[(size_t)oc * NVOX];
  }
  const float g0 = 1.f / (1.f + expf(-s[20]));
  const float g1 = 1.f / (1.f + expf(-s[21]));
  const float g2 = 1.f / (1.f + expf(-s[22]));
  float* __restrict__ op = out + (size_t)b * 20 * NVOX + vox;
#pragma unroll
  for (int c = 0; c < 5; ++c) op[(size_t)c * NVOX] = fmaxf(s[c], 0.f);
#pragma unroll
  for (int c = 0; c < 3; ++c) op[(size_t)(5 + c) * NVOX] = s[5 + c] * g0;
#pragma unroll
  for (int c = 0; c < 5; ++c) op[(size_t)(8 + c) * NVOX] = s[8 + c] * g1;
#pragma unroll
  for (int c = 0; c < 7; ++c) op[(size_t)(13 + c) * NVOX] = s[13 + c] * g2;
}

// AvgSpacial over P2 partials [G][16][20][1000] + fc1(relu) + fc2.
template <int G>
__global__ __launch_bounds__(THREADS)
void head_kernel(const float* __restrict__ P2,
                 const float* __restrict__ fc1w, const float* __restrict__ fc1b,
                 const float* __restrict__ fc2w, const float* __restrict__ fc2b,
                 float* __restrict__ out) {
  const int b = blockIdx.x;
  const int t = threadIdx.x;
  __shared__ float part[200];
  __shared__ float xm[20];
  __shared__ float h[50];
  if (t < 200) {
    const int ch = t / 10, seg = t % 10;
    float s = 0.f;
    for (int g = 0; g < G; ++g) {
      const float* __restrict__ p = P2 + ((size_t)(g * BATCH + b) * 20 + ch) * 1000 + seg * 100;
      for (int i = 0; i < 100; ++i) s += p[i];
    }
    part[t] = s;
  }
  __syncthreads();
  if (t < 20) {
    float s = 0.f;
    for (int i = 0; i < 10; ++i) s += part[t * 10 + i];
    xm[t] = s * (1.0f / 1000.0f);
  }
  __syncthreads();
  if (t < 50) {
    float s = fc1b[t];
    for (int c = 0; c < 20; ++c) s += xm[c] * fc1w[t * 20 + c];
    h[t] = fmaxf(s, 0.f);
  }
  __syncthreads();
  if (t < 2) {
    float s = fc2b[t];
    for (int k = 0; k < 50; ++k) s += h[k] * fc2w[t * 50 + k];
    out[b * 2 + t] = s;
  }
}

extern "C" void kernel_launch(void* const* d_in, const int* in_sizes, int n_in,
                              void* d_out, int out_size, void* d_ws, size_t ws_size,
                              hipStream_t stream) {
  (void)in_sizes; (void)n_in; (void)out_size;
  const float* inp  = (const float*)d_in[0];
  const float* W0   = (const float*)d_in[1];
  const float* W1   = (const float*)d_in[2];
  const float* W2   = (const float*)d_in[3];
  const float* fc1w = (const float*)d_in[4];
  const float* fc1b = (const float*)d_in[5];
  const float* fc2w = (const float*)d_in[6];
  const float* fc2b = (const float*)d_in[7];
  float* out = (float*)d_out;

  float* ws = (float*)d_ws;
  float* K0 = ws;
  float* K1 = K0 + 2875;
  float* K2 = K1 + 57500;
  float* A0 = K2 + 50000;
  float* A1 = A0 + (size_t)11499840;
  float* P1 = A1 + (size_t)1866240;
  float* P2 = A0;  // A0 is dead after combine; conv2 partials alias it

  const size_t favail = ws_size / 4;
  const size_t fixed = 2875 + 57500 + 50000 + (size_t)11499840 + 1866240;  // 13,476,455

  hipLaunchKernelGGL(synth_kernel, dim3(1), dim3(256), 0, stream, W0, W1, W2, K0, K1, K2);

  // conv0: NX=2 -> XS=17, SPI=33*33*17=18513, NB=73.
  hipLaunchKernelGGL((conv_kernel<1, 1, 23, 64, 33, 2, 1>), dim3(16 * 73), dim3(THREADS), 0,
                     stream, inp, K0, A0);

  if (favail >= fixed + (size_t)5 * BATCH * 23 * 5832) {
    // Tier A: conv1 ICG=4 x G=5. NX=2 -> SPI=18*18*9=2916, NB=12.
    hipLaunchKernelGGL((conv_kernel<20, 4, 23, 33, 18, 2, 0>), dim3(16 * 5 * 12), dim3(THREADS), 0,
                       stream, A0, K1, P1);
    hipLaunchKernelGGL((combine_gate_kernel<5, 5832>), dim3((16 * 5832 + THREADS - 1) / THREADS),
                       dim3(THREADS), 0, stream, P1, A1);
    // conv2 ICG=1 x G=20, NX=2: SPI=10*10*5=500, NB=2.
    hipLaunchKernelGGL((conv_kernel<20, 1, 20, 18, 10, 2, 0>), dim3(16 * 20 * 2), dim3(THREADS), 0,
                       stream, A1, K2, P2);
    hipLaunchKernelGGL((head_kernel<20>), dim3(BATCH), dim3(THREADS), 0, stream, P2, fc1w, fc1b,
                       fc2w, fc2b, out);
  } else if (favail >= fixed + (size_t)4 * BATCH * 23 * 5832) {
    // Tier B: conv1 ICG=5 x G=4.
    hipLaunchKernelGGL((conv_kernel<20, 5, 23, 33, 18, 2, 0>), dim3(16 * 4 * 12), dim3(THREADS), 0,
                       stream, A0, K1, P1);
    hipLaunchKernelGGL((combine_gate_kernel<4, 5832>), dim3((16 * 5832 + THREADS - 1) / THREADS),
                       dim3(THREADS), 0, stream, P1, A1);
    hipLaunchKernelGGL((conv_kernel<20, 1, 20, 18, 10, 2, 0>), dim3(16 * 20 * 2), dim3(THREADS), 0,
                       stream, A1, K2, P2);
    hipLaunchKernelGGL((head_kernel<20>), dim3(BATCH), dim3(THREADS), 0, stream, P2, fc1w, fc1b,
                       fc2w, fc2b, out);
  } else {
    // Tier C: fused fallback, no partials. A2 goes where P1 would.
    float* A2 = P1;
    hipLaunchKernelGGL((conv_kernel<20, 20, 23, 33, 18, 2, 1>), dim3(16 * 12), dim3(THREADS), 0,
                       stream, A0, K1, A1);
    hipLaunchKernelGGL((conv_kernel<20, 20, 20, 18, 10, 2, 2>), dim3(16 * 2), dim3(THREADS), 0,
                       stream, A1, K2, A2);
    hipLaunchKernelGGL((head_kernel<1>), dim3(BATCH), dim3(THREADS), 0, stream, A2, fc1w, fc1b,
                       fc2w, fc2b, out);
  }
}

// Round 5
// 504.301 us; speedup vs baseline: 12.8740x; 12.8740x over previous
//
#include <hip/hip_runtime.h>
#include <math.h>

#define THREADS 256
constexpr int BATCH = 16;

// ---------------------------------------------------------------------------
// Workspace layout (floats):
//   K0t [125][23]        : 2875      K1t [20][125][23] : 57500
//   K2t [20][125][20]    : 50000
//   A0  [16][20][33^3]   : 11,499,840   (P2 aliases this region after combine)
//   A1  [16][20][18^3]   : 1,866,240
//   P1  [G1][16][23][18^3]  (tier A: G1=5 -> 10,730,880 fl; total 96.8 MB)
// ---------------------------------------------------------------------------

__global__ void synth_kernel(const float* __restrict__ W0,
                             const float* __restrict__ W1,
                             const float* __restrict__ W2,
                             float* __restrict__ K0,
                             float* __restrict__ K1,
                             float* __restrict__ K2) {
  __shared__ float Bsh[3][128];
  __shared__ float nrm[3];
  const int t = threadIdx.x;
  if (t < 125) {
    float dz = (float)(t / 25) - 2.0f;
    float dy = (float)((t / 5) % 5) - 2.0f;
    float dx = (float)(t % 5) - 2.0f;
    float r = sqrtf(dx * dx + dy * dy + dz * dz);
    for (int j = 0; j < 3; ++j) {
      float d = (r - (float)j) * (1.0f / 0.6f);
      Bsh[j][t] = expf(-0.5f * d * d);
    }
  }
  __syncthreads();
  if (t < 3) {
    float s = 0.f;
    for (int k = 0; k < 125; ++k) s += Bsh[t][k] * Bsh[t][k];
    nrm[t] = rsqrtf(s);
  }
  __syncthreads();
  if (t < 125) {
    for (int j = 0; j < 3; ++j) Bsh[j][t] *= nrm[j];
  }
  __syncthreads();
  for (int i = t; i < 125 * 23; i += blockDim.x) {
    int k = i / 23, oc = i % 23;
    const float* w = W0 + oc * 3;
    K0[i] = w[0] * Bsh[0][k] + w[1] * Bsh[1][k] + w[2] * Bsh[2][k];
  }
  for (int i = t; i < 20 * 125 * 23; i += blockDim.x) {
    int oc = i % 23, k = (i / 23) % 125, ic = i / (23 * 125);
    const float* w = W1 + (oc * 20 + ic) * 3;
    K1[i] = w[0] * Bsh[0][k] + w[1] * Bsh[1][k] + w[2] * Bsh[2][k];
  }
  for (int i = t; i < 20 * 125 * 20; i += blockDim.x) {
    int oc = i % 20, k = (i / 20) % 125, ic = i / (20 * 125);
    const float* w = W2 + (oc * 20 + ic) * 3;
    K2[i] = w[0] * Bsh[0][k] + w[1] * Bsh[1][k] + w[2] * Bsh[2][k];
  }
}

// Direct conv, stride 2, pad 3, 5^3 taps. Each thread: NX x-consecutive output
// voxels, ALL OC channels of one ic-group. Weights staged in LDS (padded OCP,
// zero-filled) and read as broadcast float4. Register budget is managed
// EXPLICITLY (rounds 3/4 post-mortem: full unroll hoisted 30 float4 weight
// reads -> 120 live VGPRs -> spill): kz/ky kept as runtime loops, and
// sched_barrier(0) every 2 c4-chunks caps live weight regs at 10 float4.
// EPI: 0 = partials [g][b][OC][vox], 1 = gated (G==1, OC==23), 2 = plain.
template <int ICTOT, int ICG, int OC, int DIN, int DOUT, int NX, int EPI>
__global__ __launch_bounds__(THREADS)
void conv_kernel(const float* __restrict__ in, const float* __restrict__ K,
                 float* __restrict__ out) {
  constexpr int NVOX = DOUT * DOUT * DOUT;
  constexpr int G = ICTOT / ICG;
  constexpr int DIN3 = DIN * DIN * DIN;
  constexpr int XS = (DOUT + NX - 1) / NX;   // strips per x-row
  constexpr int SPI = DOUT * DOUT * XS;      // strips per (b,g)
  constexpr int NB = (SPI + THREADS - 1) / THREADS;
  constexpr int OCP = (OC + 3) & ~3;
  constexpr int NC4 = OCP / 4;
  constexpr int NV = 2 * NX + 3;

  __shared__ __align__(16) float wsh[125 * OCP];

  const int bid = blockIdx.x;
  const int chunk = bid % NB;
  const int gb = bid / NB;
  const int g = gb % G;
  const int b = gb / G;
  const int t = threadIdx.x;
  const int s = chunk * THREADS + t;
  const bool active = s < SPI;
  const int si = active ? s : 0;
  const int zo = si / (DOUT * XS);
  const int yo = (si / XS) % DOUT;
  const int xo0 = (si % XS) * NX;

  float acc[OCP][NX];
#pragma unroll
  for (int oc = 0; oc < OCP; ++oc)
#pragma unroll
    for (int n = 0; n < NX; ++n) acc[oc][n] = 0.f;

  const float* __restrict__ ip0 = in + (size_t)(b * ICTOT + g * ICG) * DIN3;
  const float* __restrict__ wp0 = K + (size_t)(g * ICG) * 125 * OC;

  int xic[NV];
  bool xok[NV];
#pragma unroll
  for (int p = 0; p < NV; ++p) {
    int xi = 2 * xo0 - 3 + p;
    xok[p] = (unsigned)xi < (unsigned)DIN;
    xic[p] = min(max(xi, 0), DIN - 1);
  }

#pragma unroll 1
  for (int icl = 0; icl < ICG; ++icl) {
    __syncthreads();
    for (int i = t; i < 125 * OCP; i += THREADS) {
      const int tap = i / OCP, oc = i % OCP;
      wsh[i] = (oc < OC) ? wp0[icl * 125 * OC + tap * OC + oc] : 0.f;
    }
    __syncthreads();
    const float* __restrict__ ipc = ip0 + (size_t)icl * DIN3;
#pragma unroll 1
    for (int kz = 0; kz < 5; ++kz) {
      const int zi = 2 * zo - 3 + kz;
      const bool zok = (unsigned)zi < (unsigned)DIN;
      const int zic = min(max(zi, 0), DIN - 1);
#pragma unroll 1
      for (int ky = 0; ky < 5; ++ky) {
        const int yi = 2 * yo - 3 + ky;
        const bool yzok = zok && ((unsigned)yi < (unsigned)DIN);
        const int yic = min(max(yi, 0), DIN - 1);
        const float* __restrict__ row = ipc + ((size_t)zic * DIN + yic) * DIN;
        float v[NV];
#pragma unroll
        for (int p = 0; p < NV; ++p) {
          const float val = row[xic[p]];
          v[p] = (yzok && xok[p]) ? val : 0.f;
        }
        const int kb = ((kz * 5 + ky) * 5) * OCP;
#pragma unroll
        for (int c4 = 0; c4 < NC4; ++c4) {
#pragma unroll
          for (int kx = 0; kx < 5; ++kx) {
            const float4 w4 = *(const float4*)&wsh[kb + kx * OCP + 4 * c4];
#pragma unroll
            for (int n = 0; n < NX; ++n) {
              acc[c4 * 4 + 0][n] = fmaf(w4.x, v[2 * n + kx], acc[c4 * 4 + 0][n]);
              acc[c4 * 4 + 1][n] = fmaf(w4.y, v[2 * n + kx], acc[c4 * 4 + 1][n]);
              acc[c4 * 4 + 2][n] = fmaf(w4.z, v[2 * n + kx], acc[c4 * 4 + 2][n]);
              acc[c4 * 4 + 3][n] = fmaf(w4.w, v[2 * n + kx], acc[c4 * 4 + 3][n]);
            }
          }
          if ((c4 & 1) || c4 == NC4 - 1) __builtin_amdgcn_sched_barrier(0);
        }
      }
    }
  }

  if (!active) return;
  const int vbase = (zo * DOUT + yo) * DOUT + xo0;

  if constexpr (EPI == 1) {
    float* __restrict__ op = out + (size_t)b * 20 * NVOX + vbase;
#pragma unroll
    for (int n = 0; n < NX; ++n) {
      if (xo0 + n < DOUT) {
        const float g0 = 1.f / (1.f + expf(-acc[20][n]));
        const float g1 = 1.f / (1.f + expf(-acc[21][n]));
        const float g2 = 1.f / (1.f + expf(-acc[22][n]));
#pragma unroll
        for (int c = 0; c < 5; ++c) op[(size_t)c * NVOX + n] = fmaxf(acc[c][n], 0.f);
#pragma unroll
        for (int c = 0; c < 3; ++c) op[(size_t)(5 + c) * NVOX + n] = acc[5 + c][n] * g0;
#pragma unroll
        for (int c = 0; c < 5; ++c) op[(size_t)(8 + c) * NVOX + n] = acc[8 + c][n] * g1;
#pragma unroll
        for (int c = 0; c < 7; ++c) op[(size_t)(13 + c) * NVOX + n] = acc[13 + c][n] * g2;
      }
    }
  } else if constexpr (EPI == 0) {
    float* __restrict__ op = out + ((size_t)(g * BATCH + b) * OC) * NVOX + vbase;
#pragma unroll
    for (int oc = 0; oc < OC; ++oc)
#pragma unroll
      for (int n = 0; n < NX; ++n)
        if (xo0 + n < DOUT) op[(size_t)oc * NVOX + n] = acc[oc][n];
  } else {
    float* __restrict__ op = out + (size_t)b * OC * NVOX + vbase;
#pragma unroll
    for (int oc = 0; oc < OC; ++oc)
#pragma unroll
      for (int n = 0; n < NX; ++n)
        if (xo0 + n < DOUT) op[(size_t)oc * NVOX + n] = acc[oc][n];
  }
}

// Sum ic-group partials (23 ch) + gating -> 20 ch output.
template <int G, int NVOX>
__global__ __launch_bounds__(THREADS)
void combine_gate_kernel(const float* __restrict__ P, float* __restrict__ out) {
  const int tid = blockIdx.x * THREADS + threadIdx.x;
  if (tid >= BATCH * NVOX) return;
  const int vox = tid % NVOX;
  const int b = tid / NVOX;
  float s[23];
#pragma unroll
  for (int oc = 0; oc < 23; ++oc) s[oc] = 0.f;
  for (int g = 0; g < G; ++g) {
    const float* __restrict__ p = P + ((size_t)(g * BATCH + b) * 23) * NVOX + vox;
#pragma unroll
    for (int oc = 0; oc < 23; ++oc) s[oc] += p[(size_t)oc * NVOX];
  }
  const float g0 = 1.f / (1.f + expf(-s[20]));
  const float g1 = 1.f / (1.f + expf(-s[21]));
  const float g2 = 1.f / (1.f + expf(-s[22]));
  float* __restrict__ op = out + (size_t)b * 20 * NVOX + vox;
#pragma unroll
  for (int c = 0; c < 5; ++c) op[(size_t)c * NVOX] = fmaxf(s[c], 0.f);
#pragma unroll
  for (int c = 0; c < 3; ++c) op[(size_t)(5 + c) * NVOX] = s[5 + c] * g0;
#pragma unroll
  for (int c = 0; c < 5; ++c) op[(size_t)(8 + c) * NVOX] = s[8 + c] * g1;
#pragma unroll
  for (int c = 0; c < 7; ++c) op[(size_t)(13 + c) * NVOX] = s[13 + c] * g2;
}

// AvgSpacial over P2 partials [G][16][20][1000] + fc1(relu) + fc2.
template <int G>
__global__ __launch_bounds__(THREADS)
void head_kernel(const float* __restrict__ P2,
                 const float* __restrict__ fc1w, const float* __restrict__ fc1b,
                 const float* __restrict__ fc2w, const float* __restrict__ fc2b,
                 float* __restrict__ out) {
  const int b = blockIdx.x;
  const int t = threadIdx.x;
  __shared__ float part[200];
  __shared__ float xm[20];
  __shared__ float h[50];
  if (t < 200) {
    const int ch = t / 10, seg = t % 10;
    float s = 0.f;
    for (int g = 0; g < G; ++g) {
      const float* __restrict__ p = P2 + ((size_t)(g * BATCH + b) * 20 + ch) * 1000 + seg * 100;
      for (int i = 0; i < 100; ++i) s += p[i];
    }
    part[t] = s;
  }
  __syncthreads();
  if (t < 20) {
    float s = 0.f;
    for (int i = 0; i < 10; ++i) s += part[t * 10 + i];
    xm[t] = s * (1.0f / 1000.0f);
  }
  __syncthreads();
  if (t < 50) {
    float s = fc1b[t];
    for (int c = 0; c < 20; ++c) s += xm[c] * fc1w[t * 20 + c];
    h[t] = fmaxf(s, 0.f);
  }
  __syncthreads();
  if (t < 2) {
    float s = fc2b[t];
    for (int k = 0; k < 50; ++k) s += h[k] * fc2w[t * 50 + k];
    out[b * 2 + t] = s;
  }
}

extern "C" void kernel_launch(void* const* d_in, const int* in_sizes, int n_in,
                              void* d_out, int out_size, void* d_ws, size_t ws_size,
                              hipStream_t stream) {
  (void)in_sizes; (void)n_in; (void)out_size;
  const float* inp  = (const float*)d_in[0];
  const float* W0   = (const float*)d_in[1];
  const float* W1   = (const float*)d_in[2];
  const float* W2   = (const float*)d_in[3];
  const float* fc1w = (const float*)d_in[4];
  const float* fc1b = (const float*)d_in[5];
  const float* fc2w = (const float*)d_in[6];
  const float* fc2b = (const float*)d_in[7];
  float* out = (float*)d_out;

  float* ws = (float*)d_ws;
  float* K0 = ws;
  float* K1 = K0 + 2875;
  float* K2 = K1 + 57500;
  float* A0 = K2 + 50000;
  float* A1 = A0 + (size_t)11499840;
  float* P1 = A1 + (size_t)1866240;
  float* P2 = A0;  // A0 is dead after combine; conv2 partials alias it

  const size_t favail = ws_size / 4;
  const size_t fixed = 2875 + 57500 + 50000 + (size_t)11499840 + 1866240;  // 13,476,455

  hipLaunchKernelGGL(synth_kernel, dim3(1), dim3(256), 0, stream, W0, W1, W2, K0, K1, K2);

  // conv0: NX=2 -> XS=17, SPI=33*33*17=18513, NB=73.
  hipLaunchKernelGGL((conv_kernel<1, 1, 23, 64, 33, 2, 1>), dim3(16 * 73), dim3(THREADS), 0,
                     stream, inp, K0, A0);

  if (favail >= fixed + (size_t)5 * BATCH * 23 * 5832) {
    // Tier A: conv1 ICG=4 x G=5. NX=2 -> SPI=18*18*9=2916, NB=12.
    hipLaunchKernelGGL((conv_kernel<20, 4, 23, 33, 18, 2, 0>), dim3(16 * 5 * 12), dim3(THREADS), 0,
                       stream, A0, K1, P1);
    hipLaunchKernelGGL((combine_gate_kernel<5, 5832>), dim3((16 * 5832 + THREADS - 1) / THREADS),
                       dim3(THREADS), 0, stream, P1, A1);
    // conv2 ICG=1 x G=20, NX=2: SPI=10*10*5=500, NB=2.
    hipLaunchKernelGGL((conv_kernel<20, 1, 20, 18, 10, 2, 0>), dim3(16 * 20 * 2), dim3(THREADS), 0,
                       stream, A1, K2, P2);
    hipLaunchKernelGGL((head_kernel<20>), dim3(BATCH), dim3(THREADS), 0, stream, P2, fc1w, fc1b,
                       fc2w, fc2b, out);
  } else if (favail >= fixed + (size_t)4 * BATCH * 23 * 5832) {
    // Tier B: conv1 ICG=5 x G=4.
    hipLaunchKernelGGL((conv_kernel<20, 5, 23, 33, 18, 2, 0>), dim3(16 * 4 * 12), dim3(THREADS), 0,
                       stream, A0, K1, P1);
    hipLaunchKernelGGL((combine_gate_kernel<4, 5832>), dim3((16 * 5832 + THREADS - 1) / THREADS),
                       dim3(THREADS), 0, stream, P1, A1);
    hipLaunchKernelGGL((conv_kernel<20, 1, 20, 18, 10, 2, 0>), dim3(16 * 20 * 2), dim3(THREADS), 0,
                       stream, A1, K2, P2);
    hipLaunchKernelGGL((head_kernel<20>), dim3(BATCH), dim3(THREADS), 0, stream, P2, fc1w, fc1b,
                       fc2w, fc2b, out);
  } else {
    // Tier C: fused fallback, no partials. A2 goes where P1 would.
    float* A2 = P1;
    hipLaunchKernelGGL((conv_kernel<20, 20, 23, 33, 18, 2, 1>), dim3(16 * 12), dim3(THREADS), 0,
                       stream, A0, K1, A1);
    hipLaunchKernelGGL((conv_kernel<20, 20, 20, 18, 10, 2, 2>), dim3(16 * 2), dim3(THREADS), 0,
                       stream, A1, K2, A2);
    hipLaunchKernelGGL((head_kernel<1>), dim3(BATCH), dim3(THREADS), 0, stream, A2, fc1w, fc1b,
                       fc2w, fc2b, out);
  }
}

// Round 6
// 402.847 us; speedup vs baseline: 16.1162x; 1.2518x over previous
//
#include <hip/hip_runtime.h>
#include <math.h>
#include <type_traits>

#define CTHREADS 128   // conv kernels
#define THREADS 256    // aux kernels
constexpr int BATCH = 16;

// ---------------------------------------------------------------------------
// Radial reduction: the synthesized kernel K[o,i,tap] = sum_j W[o,i,j]*B_j[tap]
// and B_j is radial: 125 taps -> 10 distinct values (r^2 in {0,1,2,3,4,5,6,8,9,12}).
// Per (voxel, ic): 125 tap-sums into 10 radial classes, then z_j = Bval[j].s (30 FMA),
// then acc[oc] += W[o,i,j] z_j (3*OCP FMA). ~8x FLOP reduction vs per-tap FMA.
//
// Workspace (floats): BV[10][4]:40  K0R[1][3][24]:72  K1R[20][3][24]:1440
//   K2R[20][3][20]:1200  A0 16*20*33^3:11,499,840  A1 16*20*18^3:1,866,240
//   P1 [G1][16][23][18^3]  (tier A G1=5: 10,730,880 -> total 96.4 MB)
//   P2 aliases A0.
// ---------------------------------------------------------------------------

__host__ __device__ constexpr int QI(int q) {  // q = ay^2+ax^2 in {0,1,2,4,5,8}
  return q == 0 ? 0 : q == 1 ? 1 : q == 2 ? 2 : q == 4 ? 3 : q == 5 ? 4 : 5;
}

__global__ void synth_kernel(const float* __restrict__ W0,
                             const float* __restrict__ W1,
                             const float* __restrict__ W2,
                             float* __restrict__ BV,
                             float* __restrict__ K0R,
                             float* __restrict__ K1R,
                             float* __restrict__ K2R) {
  __shared__ float Bsh[3][128];
  __shared__ float nrm[3];
  const int t = threadIdx.x;
  if (t < 125) {
    float dz = (float)(t / 25) - 2.0f;
    float dy = (float)((t / 5) % 5) - 2.0f;
    float dx = (float)(t % 5) - 2.0f;
    float r = sqrtf(dx * dx + dy * dy + dz * dz);
    for (int j = 0; j < 3; ++j) {
      float d = (r - (float)j) * (1.0f / 0.6f);
      Bsh[j][t] = expf(-0.5f * d * d);
    }
  }
  __syncthreads();
  if (t < 3) {
    float s = 0.f;
    for (int k = 0; k < 125; ++k) s += Bsh[t][k] * Bsh[t][k];
    nrm[t] = rsqrtf(s);
  }
  __syncthreads();
  if (t < 40) {
    const int g = t / 4, j = t % 4;
    constexpr int R2C[10] = {0, 1, 2, 3, 4, 5, 6, 8, 9, 12};
    if (j < 3) {
      float d = (sqrtf((float)R2C[g]) - (float)j) * (1.0f / 0.6f);
      BV[t] = expf(-0.5f * d * d) * nrm[j];
    } else {
      BV[t] = 0.f;
    }
  }
  // K*R layout [ic][j][OCP], oc-pad zero
  for (int i = t; i < 3 * 24; i += blockDim.x) {
    int j = i / 24, oc = i % 24;
    K0R[i] = (oc < 23) ? W0[oc * 3 + j] : 0.f;
  }
  for (int i = t; i < 20 * 3 * 24; i += blockDim.x) {
    int oc = i % 24, j = (i / 24) % 3, ic = i / 72;
    K1R[i] = (oc < 23) ? W1[(oc * 20 + ic) * 3 + j] : 0.f;
  }
  for (int i = t; i < 20 * 3 * 20; i += blockDim.x) {
    int oc = i % 20, j = (i / 20) % 3, ic = i / 60;
    K2R[i] = W2[(oc * 20 + ic) * 3 + j];
  }
}

// Direct conv via radial-class reduction. Thread = NX x-consecutive voxels, all
// OC channels of one ic-group. Register discipline (rounds 3-5 lesson): runtime
// kz loops (azc-phase split keeps all register indices compile-time),
// sched_barrier(0) per row caps load hoisting. All-ic weights staged in LDS
// once (no barriers in the main loop).
// EPI: 0 = partials [g][b][OC][vox], 1 = gated (OC==23), 2 = plain.
template <int ICTOT, int ICG, int OC, int DIN, int DOUT, int NX, int EPI>
__global__ __launch_bounds__(CTHREADS)
void conv_kernel(const float* __restrict__ in, const float* __restrict__ BV,
                 const float* __restrict__ KR, float* __restrict__ out) {
  constexpr int NVOX = DOUT * DOUT * DOUT;
  constexpr int G = ICTOT / ICG;
  constexpr int DIN3 = DIN * DIN * DIN;
  constexpr int XS = (DOUT + NX - 1) / NX;
  constexpr int SPI = DOUT * DOUT * XS;
  constexpr int NB = (SPI + CTHREADS - 1) / CTHREADS;
  constexpr int OCP = (OC + 3) & ~3;
  constexpr int NC4 = OCP / 4;
  constexpr int NV = 2 * NX + 3;

  __shared__ __align__(16) float lbv[40];
  __shared__ __align__(16) float lw[ICG * 3 * OCP];

  const int bid = blockIdx.x;
  const int chunk = bid % NB;
  const int gb = bid / NB;
  const int g = gb % G;
  const int b = gb / G;
  const int t = threadIdx.x;

  for (int i = t; i < 40; i += CTHREADS) lbv[i] = BV[i];
  for (int i = t; i < ICG * 3 * OCP; i += CTHREADS)
    lw[i] = KR[(size_t)g * ICG * 3 * OCP + i];
  __syncthreads();

  const int s = chunk * CTHREADS + t;
  const bool active = s < SPI;
  const int si = active ? s : 0;
  const int zo = si / (DOUT * XS);
  const int yo = (si / XS) % DOUT;
  const int xo0 = (si % XS) * NX;

  float acc[OCP][NX];
#pragma unroll
  for (int oc = 0; oc < OCP; ++oc)
#pragma unroll
    for (int n = 0; n < NX; ++n) acc[oc][n] = 0.f;

  const float* __restrict__ ip0 = in + (size_t)(b * ICTOT + g * ICG) * DIN3;

  int xic[NV];
  bool xok[NV];
#pragma unroll
  for (int p = 0; p < NV; ++p) {
    int xi = 2 * xo0 - 3 + p;
    xok[p] = (unsigned)xi < (unsigned)DIN;
    xic[p] = min(max(xi, 0), DIN - 1);
  }

#pragma unroll 1
  for (int icl = 0; icl < ICG; ++icl) {
    const float* __restrict__ ipc = ip0 + (size_t)icl * DIN3;
    float sg[10][NX];
#pragma unroll
    for (int gg = 0; gg < 10; ++gg)
#pragma unroll
      for (int n = 0; n < NX; ++n) sg[gg][n] = 0.f;

    // one kz-plane; AZC = az^2-class (compile time) so sg indices stay constexpr
    auto plane = [&](auto azc_c, int kz) {
      constexpr int AZC = decltype(azc_c)::value;
      constexpr int GM[3][6] = {
          {0, 1, 2, 4, 5, 7},   // az2=0: r2 = q
          {1, 2, 3, 5, 6, 8},   // az2=1
          {4, 5, 6, 7, 8, 9}};  // az2=4
      constexpr int A2[5] = {4, 1, 0, 1, 4};
      const int zi = 2 * zo - 3 + kz;
      const bool zok = (unsigned)zi < (unsigned)DIN;
      const int zic = min(max(zi, 0), DIN - 1);
      float pq[6][NX];
#pragma unroll
      for (int qi = 0; qi < 6; ++qi)
#pragma unroll
        for (int n = 0; n < NX; ++n) pq[qi][n] = 0.f;
#pragma unroll
      for (int ky = 0; ky < 5; ++ky) {
        const int yi = 2 * yo - 3 + ky;
        const bool yzok = zok && ((unsigned)yi < (unsigned)DIN);
        const int yic = min(max(yi, 0), DIN - 1);
        const float* __restrict__ row = ipc + ((size_t)zic * DIN + yic) * DIN;
        float v[NV];
#pragma unroll
        for (int p = 0; p < NV; ++p) {
          const float val = row[xic[p]];
          v[p] = (yzok && xok[p]) ? val : 0.f;
        }
#pragma unroll
        for (int kx = 0; kx < 5; ++kx)
#pragma unroll
          for (int n = 0; n < NX; ++n) pq[QI(A2[ky] + A2[kx])][n] += v[2 * n + kx];
        __builtin_amdgcn_sched_barrier(0);
      }
#pragma unroll
      for (int qi = 0; qi < 6; ++qi)
#pragma unroll
        for (int n = 0; n < NX; ++n) sg[GM[AZC][qi]][n] += pq[qi][n];
    };

    plane(std::integral_constant<int, 0>{}, 2);
#pragma unroll 1
    for (int rep = 0; rep < 2; ++rep) plane(std::integral_constant<int, 1>{}, 1 + 2 * rep);
#pragma unroll 1
    for (int rep = 0; rep < 2; ++rep) plane(std::integral_constant<int, 2>{}, 4 * rep);

    // z_j = sum_g Bval[j][g] * sg[g]
    float z[3][NX];
#pragma unroll
    for (int j = 0; j < 3; ++j)
#pragma unroll
      for (int n = 0; n < NX; ++n) z[j][n] = 0.f;
#pragma unroll
    for (int gg = 0; gg < 10; ++gg) {
      const float4 bv4 = *(const float4*)&lbv[gg * 4];
#pragma unroll
      for (int n = 0; n < NX; ++n) {
        z[0][n] = fmaf(bv4.x, sg[gg][n], z[0][n]);
        z[1][n] = fmaf(bv4.y, sg[gg][n], z[1][n]);
        z[2][n] = fmaf(bv4.z, sg[gg][n], z[2][n]);
      }
    }
    // acc[oc] += W[oc][icl][j] * z_j   (LDS broadcast float4)
#pragma unroll
    for (int j = 0; j < 3; ++j) {
#pragma unroll
      for (int c4 = 0; c4 < NC4; ++c4) {
        const float4 w4 = *(const float4*)&lw[(icl * 3 + j) * OCP + 4 * c4];
#pragma unroll
        for (int n = 0; n < NX; ++n) {
          acc[c4 * 4 + 0][n] = fmaf(w4.x, z[j][n], acc[c4 * 4 + 0][n]);
          acc[c4 * 4 + 1][n] = fmaf(w4.y, z[j][n], acc[c4 * 4 + 1][n]);
          acc[c4 * 4 + 2][n] = fmaf(w4.z, z[j][n], acc[c4 * 4 + 2][n]);
          acc[c4 * 4 + 3][n] = fmaf(w4.w, z[j][n], acc[c4 * 4 + 3][n]);
        }
      }
    }
    __builtin_amdgcn_sched_barrier(0);
  }

  if (!active) return;
  const int vbase = (zo * DOUT + yo) * DOUT + xo0;

  if constexpr (EPI == 1) {
    float* __restrict__ op = out + (size_t)b * 20 * NVOX + vbase;
#pragma unroll
    for (int n = 0; n < NX; ++n) {
      if (xo0 + n < DOUT) {
        const float g0 = 1.f / (1.f + expf(-acc[20][n]));
        const float g1 = 1.f / (1.f + expf(-acc[21][n]));
        const float g2 = 1.f / (1.f + expf(-acc[22][n]));
#pragma unroll
        for (int c = 0; c < 5; ++c) op[(size_t)c * NVOX + n] = fmaxf(acc[c][n], 0.f);
#pragma unroll
        for (int c = 0; c < 3; ++c) op[(size_t)(5 + c) * NVOX + n] = acc[5 + c][n] * g0;
#pragma unroll
        for (int c = 0; c < 5; ++c) op[(size_t)(8 + c) * NVOX + n] = acc[8 + c][n] * g1;
#pragma unroll
        for (int c = 0; c < 7; ++c) op[(size_t)(13 + c) * NVOX + n] = acc[13 + c][n] * g2;
      }
    }
  } else if constexpr (EPI == 0) {
    float* __restrict__ op = out + ((size_t)(g * BATCH + b) * OC) * NVOX + vbase;
#pragma unroll
    for (int oc = 0; oc < OC; ++oc)
#pragma unroll
      for (int n = 0; n < NX; ++n)
        if (xo0 + n < DOUT) op[(size_t)oc * NVOX + n] = acc[oc][n];
  } else {
    float* __restrict__ op = out + (size_t)b * OC * NVOX + vbase;
#pragma unroll
    for (int oc = 0; oc < OC; ++oc)
#pragma unroll
      for (int n = 0; n < NX; ++n)
        if (xo0 + n < DOUT) op[(size_t)oc * NVOX + n] = acc[oc][n];
  }
}

// Sum ic-group partials (23 ch) + gating -> 20 ch output.
template <int G, int NVOX>
__global__ __launch_bounds__(THREADS)
void combine_gate_kernel(const float* __restrict__ P, float* __restrict__ out) {
  const int tid = blockIdx.x * THREADS + threadIdx.x;
  if (tid >= BATCH * NVOX) return;
  const int vox = tid % NVOX;
  const int b = tid / NVOX;
  float s[23];
#pragma unroll
  for (int oc = 0; oc < 23; ++oc) s[oc] = 0.f;
  for (int g = 0; g < G; ++g) {
    const float* __restrict__ p = P + ((size_t)(g * BATCH + b) * 23) * NVOX + vox;
#pragma unroll
    for (int oc = 0; oc < 23; ++oc) s[oc] += p[(size_t)oc * NVOX];
  }
  const float g0 = 1.f / (1.f + expf(-s[20]));
  const float g1 = 1.f / (1.f + expf(-s[21]));
  const float g2 = 1.f / (1.f + expf(-s[22]));
  float* __restrict__ op = out + (size_t)b * 20 * NVOX + vox;
#pragma unroll
  for (int c = 0; c < 5; ++c) op[(size_t)c * NVOX] = fmaxf(s[c], 0.f);
#pragma unroll
  for (int c = 0; c < 3; ++c) op[(size_t)(5 + c) * NVOX] = s[5 + c] * g0;
#pragma unroll
  for (int c = 0; c < 5; ++c) op[(size_t)(8 + c) * NVOX] = s[8 + c] * g1;
#pragma unroll
  for (int c = 0; c < 7; ++c) op[(size_t)(13 + c) * NVOX] = s[13 + c] * g2;
}

// AvgSpacial over P2 partials [G][16][20][1000] + fc1(relu) + fc2.
template <int G>
__global__ __launch_bounds__(THREADS)
void head_kernel(const float* __restrict__ P2,
                 const float* __restrict__ fc1w, const float* __restrict__ fc1b,
                 const float* __restrict__ fc2w, const float* __restrict__ fc2b,
                 float* __restrict__ out) {
  const int b = blockIdx.x;
  const int t = threadIdx.x;
  __shared__ float part[200];
  __shared__ float xm[20];
  __shared__ float h[50];
  if (t < 200) {
    const int ch = t / 10, seg = t % 10;
    float s = 0.f;
    for (int g = 0; g < G; ++g) {
      const float* __restrict__ p = P2 + ((size_t)(g * BATCH + b) * 20 + ch) * 1000 + seg * 100;
      for (int i = 0; i < 100; ++i) s += p[i];
    }
    part[t] = s;
  }
  __syncthreads();
  if (t < 20) {
    float s = 0.f;
    for (int i = 0; i < 10; ++i) s += part[t * 10 + i];
    xm[t] = s * (1.0f / 1000.0f);
  }
  __syncthreads();
  if (t < 50) {
    float s = fc1b[t];
    for (int c = 0; c < 20; ++c) s += xm[c] * fc1w[t * 20 + c];
    h[t] = fmaxf(s, 0.f);
  }
  __syncthreads();
  if (t < 2) {
    float s = fc2b[t];
    for (int k = 0; k < 50; ++k) s += h[k] * fc2w[t * 50 + k];
    out[b * 2 + t] = s;
  }
}

extern "C" void kernel_launch(void* const* d_in, const int* in_sizes, int n_in,
                              void* d_out, int out_size, void* d_ws, size_t ws_size,
                              hipStream_t stream) {
  (void)in_sizes; (void)n_in; (void)out_size;
  const float* inp  = (const float*)d_in[0];
  const float* W0   = (const float*)d_in[1];
  const float* W1   = (const float*)d_in[2];
  const float* W2   = (const float*)d_in[3];
  const float* fc1w = (const float*)d_in[4];
  const float* fc1b = (const float*)d_in[5];
  const float* fc2w = (const float*)d_in[6];
  const float* fc2b = (const float*)d_in[7];
  float* out = (float*)d_out;

  float* ws = (float*)d_ws;
  float* BV  = ws;
  float* K0R = BV + 40;
  float* K1R = K0R + 72;
  float* K2R = K1R + 1440;
  float* A0  = K2R + 1200;
  float* A1  = A0 + (size_t)11499840;
  float* P1  = A1 + (size_t)1866240;
  float* P2  = A0;  // A0 dead after conv1; conv2 partials alias it

  const size_t favail = ws_size / 4;
  const size_t fixed = 40 + 72 + 1440 + 1200 + (size_t)11499840 + 1866240;  // 13,368,832

  hipLaunchKernelGGL(synth_kernel, dim3(1), dim3(256), 0, stream, W0, W1, W2, BV, K0R, K1R, K2R);

  // conv0: SPI=33*33*17=18513, NB=145
  hipLaunchKernelGGL((conv_kernel<1, 1, 23, 64, 33, 2, 1>), dim3(16 * 145), dim3(CTHREADS), 0,
                     stream, inp, BV, K0R, A0);

  if (favail >= fixed + (size_t)5 * BATCH * 23 * 5832) {
    // Tier A: conv1 ICG=4 x G=5. SPI=18*18*9=2916, NB=23.
    hipLaunchKernelGGL((conv_kernel<20, 4, 23, 33, 18, 2, 0>), dim3(16 * 5 * 23), dim3(CTHREADS),
                       0, stream, A0, BV, K1R, P1);
    hipLaunchKernelGGL((combine_gate_kernel<5, 5832>), dim3((16 * 5832 + THREADS - 1) / THREADS),
                       dim3(THREADS), 0, stream, P1, A1);
    // conv2 ICG=2 x G=10: SPI=10*10*5=500, NB=4.
    hipLaunchKernelGGL((conv_kernel<20, 2, 20, 18, 10, 2, 0>), dim3(16 * 10 * 4), dim3(CTHREADS),
                       0, stream, A1, BV, K2R, P2);
    hipLaunchKernelGGL(head_kernel<10>, dim3(BATCH), dim3(THREADS), 0, stream, P2, fc1w, fc1b,
                       fc2w, fc2b, out);
  } else if (favail >= fixed + (size_t)4 * BATCH * 23 * 5832) {
    // Tier B: conv1 ICG=5 x G=4.
    hipLaunchKernelGGL((conv_kernel<20, 5, 23, 33, 18, 2, 0>), dim3(16 * 4 * 23), dim3(CTHREADS),
                       0, stream, A0, BV, K1R, P1);
    hipLaunchKernelGGL((combine_gate_kernel<4, 5832>), dim3((16 * 5832 + THREADS - 1) / THREADS),
                       dim3(THREADS), 0, stream, P1, A1);
    hipLaunchKernelGGL((conv_kernel<20, 2, 20, 18, 10, 2, 0>), dim3(16 * 10 * 4), dim3(CTHREADS),
                       0, stream, A1, BV, K2R, P2);
    hipLaunchKernelGGL(head_kernel<10>, dim3(BATCH), dim3(THREADS), 0, stream, P2, fc1w, fc1b,
                       fc2w, fc2b, out);
  } else {
    // Tier C: fused fallback, no partials.
    float* A2 = P1;
    hipLaunchKernelGGL((conv_kernel<20, 20, 23, 33, 18, 2, 1>), dim3(16 * 23), dim3(CTHREADS), 0,
                       stream, A0, BV, K1R, A1);
    hipLaunchKernelGGL((conv_kernel<20, 20, 20, 18, 10, 2, 2>), dim3(16 * 4), dim3(CTHREADS), 0,
                       stream, A1, BV, K2R, A2);
    hipLaunchKernelGGL(head_kernel<1>, dim3(BATCH), dim3(THREADS), 0, stream, A2, fc1w, fc1b,
                       fc2w, fc2b, out);
  }
}

// Round 7
// 264.062 us; speedup vs baseline: 24.5865x; 1.5256x over previous
//
#include <hip/hip_runtime.h>
#include <math.h>
#include <type_traits>

#define CTHREADS 128   // conv kernels
#define THREADS 256    // aux kernels
constexpr int BATCH = 16;

// ---------------------------------------------------------------------------
// Radial reduction (round 6) + vectorized loads (round 7):
// K[o,i,tap] = sum_j W[o,i,j]*B_j[tap]; B_j radial -> 10 classes by r^2.
// Per (voxel, ic): 125 masked tap-adds into 10 classes, z_j = BV[j].s, then
// acc[oc] += W z_j. Inputs stored with PADDED row strides (16B-aligned rows)
// so each tap-row is 2 aligned float4 loads; all edge clamps only affect
// lanes that are masked to zero.
//
// Workspace (floats):
//   BV 40 | K0R 72 | K1R 1440 | K2R 1200
//   A0 [16][20][33][33][36] : 12,545,280   (rows padded 33->36)
//   A1 [16][20][18][18][20] :  2,073,600   (rows padded 18->20)
//   P1 [G1][16][23][5832]   (packed; tier B G1=4: 8,584,704 -> 92.8 MB total)
//   P2 [10][16][20][1000] aliases A0.
// ---------------------------------------------------------------------------

__host__ __device__ constexpr int QI(int q) {  // q = ay^2+ax^2 in {0,1,2,4,5,8}
  return q == 0 ? 0 : q == 1 ? 1 : q == 2 ? 2 : q == 4 ? 3 : q == 5 ? 4 : 5;
}

__global__ void synth_kernel(const float* __restrict__ W0,
                             const float* __restrict__ W1,
                             const float* __restrict__ W2,
                             float* __restrict__ BV,
                             float* __restrict__ K0R,
                             float* __restrict__ K1R,
                             float* __restrict__ K2R) {
  __shared__ float Bsh[3][128];
  __shared__ float nrm[3];
  const int t = threadIdx.x;
  if (t < 125) {
    float dz = (float)(t / 25) - 2.0f;
    float dy = (float)((t / 5) % 5) - 2.0f;
    float dx = (float)(t % 5) - 2.0f;
    float r = sqrtf(dx * dx + dy * dy + dz * dz);
    for (int j = 0; j < 3; ++j) {
      float d = (r - (float)j) * (1.0f / 0.6f);
      Bsh[j][t] = expf(-0.5f * d * d);
    }
  }
  __syncthreads();
  if (t < 3) {
    float s = 0.f;
    for (int k = 0; k < 125; ++k) s += Bsh[t][k] * Bsh[t][k];
    nrm[t] = rsqrtf(s);
  }
  __syncthreads();
  if (t < 40) {
    const int g = t / 4, j = t % 4;
    constexpr int R2C[10] = {0, 1, 2, 3, 4, 5, 6, 8, 9, 12};
    if (j < 3) {
      float d = (sqrtf((float)R2C[g]) - (float)j) * (1.0f / 0.6f);
      BV[t] = expf(-0.5f * d * d) * nrm[j];
    } else {
      BV[t] = 0.f;
    }
  }
  // K*R layout [ic][j][OCP], oc-pad zero
  for (int i = t; i < 3 * 24; i += blockDim.x) {
    int j = i / 24, oc = i % 24;
    K0R[i] = (oc < 23) ? W0[oc * 3 + j] : 0.f;
  }
  for (int i = t; i < 20 * 3 * 24; i += blockDim.x) {
    int oc = i % 24, j = (i / 24) % 3, ic = i / 72;
    K1R[i] = (oc < 23) ? W1[(oc * 20 + ic) * 3 + j] : 0.f;
  }
  for (int i = t; i < 20 * 3 * 20; i += blockDim.x) {
    int oc = i % 20, j = (i / 20) % 3, ic = i / 60;
    K2R[i] = W2[(oc * 20 + ic) * 3 + j];
  }
}

// Direct conv via radial classes. Thread = 2 x-consecutive voxels (xo0 even ->
// aligned float4 pair per tap-row). Block additionally selects an oc-chunk
// (och of OCB, C4N float4-columns each) -> 2x blocks for free.
// No sched_barriers: MLP within/across planes is wanted; register safety from
// runtime kz/rep/icl loop structure (static body = 1 plane = 10 loads).
// EPI: 0 = partials [g][b][OC][vox] packed, 1 = gated 20ch (OCB=1), 2 = plain.
template <int ICTOT, int ICG, int OC, int OCP, int DIN, int DOUT, int IRS, int ORS,
          int OCB, int C4N, int EPI>
__global__ __launch_bounds__(CTHREADS)
void conv_kernel(const float* __restrict__ in, const float* __restrict__ BV,
                 const float* __restrict__ KR, float* __restrict__ out) {
  constexpr int G = ICTOT / ICG;
  constexpr int ISLAB = DIN * DIN * IRS;
  constexpr int OSLAB = DOUT * DOUT * ORS;
  constexpr int XS = (DOUT + 1) / 2;
  constexpr int SPI = DOUT * DOUT * XS;
  constexpr int NB = (SPI + CTHREADS - 1) / CTHREADS;
  constexpr int CW = C4N * 4;

  __shared__ __align__(16) float lbv[40];
  __shared__ __align__(16) float lw[ICG * 3 * CW];

  const int bid = blockIdx.x;
  const int chunk = bid % NB;
  int rest = bid / NB;
  const int och = rest % OCB;
  rest /= OCB;
  const int g = rest % G;
  const int b = rest / G;
  const int c4lo = och * C4N;
  const int t = threadIdx.x;

  for (int i = t; i < 40; i += CTHREADS) lbv[i] = BV[i];
  for (int i = t; i < ICG * 3 * CW; i += CTHREADS) {
    const int cc = i % CW;
    const int jj = (i / CW) % 3;
    const int icl = i / (3 * CW);
    const int col = c4lo * 4 + cc;
    lw[i] = (col < OCP) ? KR[((size_t)(g * ICG + icl) * 3 + jj) * OCP + col] : 0.f;
  }
  __syncthreads();

  const int s = chunk * CTHREADS + t;
  const bool active = s < SPI;
  const int si = active ? s : 0;
  const int zo = si / (DOUT * XS);
  const int yo = (si / XS) % DOUT;
  const int xo0 = (si % XS) * 2;

  float acc[CW][2];
#pragma unroll
  for (int c = 0; c < CW; ++c) {
    acc[c][0] = 0.f;
    acc[c][1] = 0.f;
  }

  const float* __restrict__ ip0 = in + (size_t)(b * ICTOT + g * ICG) * ISLAB;
  // aligned float4 pair covering xi = 2*xo0-4 .. 2*xo0+3; clamps only affect
  // lanes masked by xok (proved per-edge: low edge lanes xi<0 masked, high
  // edge lanes xi>=DIN masked).
  const int offA = max(2 * xo0 - 4, 0);
  const int offB = min(2 * xo0, IRS - 4);
  bool xok[7];
#pragma unroll
  for (int p = 0; p < 7; ++p) xok[p] = (unsigned)(2 * xo0 - 3 + p) < (unsigned)DIN;

#pragma unroll 1
  for (int icl = 0; icl < ICG; ++icl) {
    const float* __restrict__ ipc = ip0 + (size_t)icl * ISLAB;
    float sg[10][2];
#pragma unroll
    for (int gg = 0; gg < 10; ++gg) {
      sg[gg][0] = 0.f;
      sg[gg][1] = 0.f;
    }

    auto plane = [&](auto azc_c, int kz) {
      constexpr int AZC = decltype(azc_c)::value;
      constexpr int GM[3][6] = {
          {0, 1, 2, 4, 5, 7}, {1, 2, 3, 5, 6, 8}, {4, 5, 6, 7, 8, 9}};
      constexpr int A2[5] = {4, 1, 0, 1, 4};
      const int zi = 2 * zo - 3 + kz;
      const bool zok = (unsigned)zi < (unsigned)DIN;
      const int zic = min(max(zi, 0), DIN - 1);
      float pq[6][2];
#pragma unroll
      for (int qi = 0; qi < 6; ++qi) {
        pq[qi][0] = 0.f;
        pq[qi][1] = 0.f;
      }
#pragma unroll
      for (int ky = 0; ky < 5; ++ky) {
        const int yi = 2 * yo - 3 + ky;
        const bool yzok = zok && ((unsigned)yi < (unsigned)DIN);
        const int yic = min(max(yi, 0), DIN - 1);
        const float* __restrict__ row = ipc + ((size_t)zic * DIN + yic) * IRS;
        const float4 va = *(const float4*)(row + offA);
        const float4 vb = *(const float4*)(row + offB);
        float v[7] = {va.y, va.z, va.w, vb.x, vb.y, vb.z, vb.w};
#pragma unroll
        for (int p = 0; p < 7; ++p) v[p] = (yzok && xok[p]) ? v[p] : 0.f;
#pragma unroll
        for (int kx = 0; kx < 5; ++kx) {
          pq[QI(A2[ky] + A2[kx])][0] += v[kx];
          pq[QI(A2[ky] + A2[kx])][1] += v[2 + kx];
        }
      }
#pragma unroll
      for (int qi = 0; qi < 6; ++qi) {
        sg[GM[AZC][qi]][0] += pq[qi][0];
        sg[GM[AZC][qi]][1] += pq[qi][1];
      }
    };

    plane(std::integral_constant<int, 0>{}, 2);
#pragma unroll 1
    for (int rep = 0; rep < 2; ++rep) plane(std::integral_constant<int, 1>{}, 1 + 2 * rep);
#pragma unroll 1
    for (int rep = 0; rep < 2; ++rep) plane(std::integral_constant<int, 2>{}, 4 * rep);

    float z[3][2];
#pragma unroll
    for (int j = 0; j < 3; ++j) {
      z[j][0] = 0.f;
      z[j][1] = 0.f;
    }
#pragma unroll
    for (int gg = 0; gg < 10; ++gg) {
      const float4 bv4 = *(const float4*)&lbv[gg * 4];
#pragma unroll
      for (int n = 0; n < 2; ++n) {
        z[0][n] = fmaf(bv4.x, sg[gg][n], z[0][n]);
        z[1][n] = fmaf(bv4.y, sg[gg][n], z[1][n]);
        z[2][n] = fmaf(bv4.z, sg[gg][n], z[2][n]);
      }
    }
#pragma unroll
    for (int j = 0; j < 3; ++j) {
#pragma unroll
      for (int c4 = 0; c4 < C4N; ++c4) {
        const float4 w4 = *(const float4*)&lw[(icl * 3 + j) * CW + 4 * c4];
#pragma unroll
        for (int n = 0; n < 2; ++n) {
          acc[c4 * 4 + 0][n] = fmaf(w4.x, z[j][n], acc[c4 * 4 + 0][n]);
          acc[c4 * 4 + 1][n] = fmaf(w4.y, z[j][n], acc[c4 * 4 + 1][n]);
          acc[c4 * 4 + 2][n] = fmaf(w4.z, z[j][n], acc[c4 * 4 + 2][n]);
          acc[c4 * 4 + 3][n] = fmaf(w4.w, z[j][n], acc[c4 * 4 + 3][n]);
        }
      }
    }
  }

  if (!active) return;
  const int vbase = (zo * DOUT + yo) * ORS + xo0;

  if constexpr (EPI == 1) {
    float* __restrict__ op = out + (size_t)b * 20 * OSLAB + vbase;
#pragma unroll
    for (int n = 0; n < 2; ++n) {
      if (xo0 + n < DOUT) {
        const float g0 = 1.f / (1.f + expf(-acc[20][n]));
        const float g1 = 1.f / (1.f + expf(-acc[21][n]));
        const float g2 = 1.f / (1.f + expf(-acc[22][n]));
#pragma unroll
        for (int c = 0; c < 5; ++c) op[(size_t)c * OSLAB + n] = fmaxf(acc[c][n], 0.f);
#pragma unroll
        for (int c = 0; c < 3; ++c) op[(size_t)(5 + c) * OSLAB + n] = acc[5 + c][n] * g0;
#pragma unroll
        for (int c = 0; c < 5; ++c) op[(size_t)(8 + c) * OSLAB + n] = acc[8 + c][n] * g1;
#pragma unroll
        for (int c = 0; c < 7; ++c) op[(size_t)(13 + c) * OSLAB + n] = acc[13 + c][n] * g2;
      }
    }
  } else if constexpr (EPI == 0) {
    float* __restrict__ op = out + ((size_t)(g * BATCH + b) * OC) * OSLAB + vbase;
#pragma unroll
    for (int c = 0; c < CW; ++c) {
      const int oc = c4lo * 4 + c;
      if (oc < OC) {
#pragma unroll
        for (int n = 0; n < 2; ++n)
          if (xo0 + n < DOUT) op[(size_t)oc * OSLAB + n] = acc[c][n];
      }
    }
  } else {
    float* __restrict__ op = out + (size_t)b * OC * OSLAB + vbase;
#pragma unroll
    for (int c = 0; c < CW; ++c) {
      const int oc = c4lo * 4 + c;
      if (oc < OC) {
#pragma unroll
        for (int n = 0; n < 2; ++n)
          if (xo0 + n < DOUT) op[(size_t)oc * OSLAB + n] = acc[c][n];
      }
    }
  }
}

// Sum ic-group partials (23 ch, packed) + gating -> A1 padded (row stride 20).
template <int G>
__global__ __launch_bounds__(THREADS)
void combine_gate_kernel(const float* __restrict__ P, float* __restrict__ out) {
  const int tid = blockIdx.x * THREADS + threadIdx.x;
  if (tid >= BATCH * 5832) return;
  const int vox = tid % 5832;
  const int b = tid / 5832;
  float s[23];
#pragma unroll
  for (int oc = 0; oc < 23; ++oc) s[oc] = 0.f;
  for (int g = 0; g < G; ++g) {
    const float* __restrict__ p = P + ((size_t)(g * BATCH + b) * 23) * 5832 + vox;
#pragma unroll
    for (int oc = 0; oc < 23; ++oc) s[oc] += p[(size_t)oc * 5832];
  }
  const float g0 = 1.f / (1.f + expf(-s[20]));
  const float g1 = 1.f / (1.f + expf(-s[21]));
  const float g2 = 1.f / (1.f + expf(-s[22]));
  const int zz = vox / 324, yy = (vox / 18) % 18, xx = vox % 18;
  float* __restrict__ op = out + (size_t)b * 20 * 6480 + (zz * 18 + yy) * 20 + xx;
#pragma unroll
  for (int c = 0; c < 5; ++c) op[(size_t)c * 6480] = fmaxf(s[c], 0.f);
#pragma unroll
  for (int c = 0; c < 3; ++c) op[(size_t)(5 + c) * 6480] = s[5 + c] * g0;
#pragma unroll
  for (int c = 0; c < 5; ++c) op[(size_t)(8 + c) * 6480] = s[8 + c] * g1;
#pragma unroll
  for (int c = 0; c < 7; ++c) op[(size_t)(13 + c) * 6480] = s[13 + c] * g2;
}

// AvgSpacial over P2 partials [G][16][20][1000] + fc1(relu) + fc2.
template <int G>
__global__ __launch_bounds__(THREADS)
void head_kernel(const float* __restrict__ P2,
                 const float* __restrict__ fc1w, const float* __restrict__ fc1b,
                 const float* __restrict__ fc2w, const float* __restrict__ fc2b,
                 float* __restrict__ out) {
  const int b = blockIdx.x;
  const int t = threadIdx.x;
  __shared__ float part[200];
  __shared__ float xm[20];
  __shared__ float h[50];
  if (t < 200) {
    const int ch = t / 10, seg = t % 10;
    float s = 0.f;
    for (int g = 0; g < G; ++g) {
      const float* __restrict__ p = P2 + ((size_t)(g * BATCH + b) * 20 + ch) * 1000 + seg * 100;
      for (int i = 0; i < 100; ++i) s += p[i];
    }
    part[t] = s;
  }
  __syncthreads();
  if (t < 20) {
    float s = 0.f;
    for (int i = 0; i < 10; ++i) s += part[t * 10 + i];
    xm[t] = s * (1.0f / 1000.0f);
  }
  __syncthreads();
  if (t < 50) {
    float s = fc1b[t];
    for (int c = 0; c < 20; ++c) s += xm[c] * fc1w[t * 20 + c];
    h[t] = fmaxf(s, 0.f);
  }
  __syncthreads();
  if (t < 2) {
    float s = fc2b[t];
    for (int k = 0; k < 50; ++k) s += h[k] * fc2w[t * 50 + k];
    out[b * 2 + t] = s;
  }
}

extern "C" void kernel_launch(void* const* d_in, const int* in_sizes, int n_in,
                              void* d_out, int out_size, void* d_ws, size_t ws_size,
                              hipStream_t stream) {
  (void)in_sizes; (void)n_in; (void)out_size;
  const float* inp  = (const float*)d_in[0];
  const float* W0   = (const float*)d_in[1];
  const float* W1   = (const float*)d_in[2];
  const float* W2   = (const float*)d_in[3];
  const float* fc1w = (const float*)d_in[4];
  const float* fc1b = (const float*)d_in[5];
  const float* fc2w = (const float*)d_in[6];
  const float* fc2b = (const float*)d_in[7];
  float* out = (float*)d_out;

  float* ws = (float*)d_ws;
  float* BV  = ws;                       // 40
  float* K0R = BV + 40;                  // 72
  float* K1R = K0R + 72;                 // 1440
  float* K2R = K1R + 1440;               // 1200
  float* A0  = K2R + 1200;               // 12,545,280 (padded rows 36)
  float* A1  = A0 + (size_t)12545280;    // 2,073,600  (padded rows 20)
  float* P1  = A1 + (size_t)2073600;     // variable
  float* P2  = A0;                       // conv2 partials alias dead A0

  const size_t favail = ws_size / 4;
  const size_t fixed = 40 + 72 + 1440 + 1200 + (size_t)12545280 + 2073600;  // 14,621,632

  hipLaunchKernelGGL(synth_kernel, dim3(1), dim3(256), 0, stream, W0, W1, W2, BV, K0R, K1R, K2R);

  // conv0: [16,1,64^3] packed -> gated -> A0 padded. SPI=33*33*17=18513, NB=145.
  hipLaunchKernelGGL((conv_kernel<1, 1, 23, 24, 64, 33, 64, 36, 1, 6, 1>), dim3(16 * 145),
                     dim3(CTHREADS), 0, stream, inp, BV, K0R, A0);

  // conv1 NB=23 (SPI=2916); conv2 NB=4 (SPI=500).
  if (favail >= fixed + (size_t)5 * BATCH * 23 * 5832) {
    // Tier A: G=5 (ICG=4), och-split x2 -> 3680 blocks.
    hipLaunchKernelGGL((conv_kernel<20, 4, 23, 24, 33, 18, 36, 18, 2, 3, 0>),
                       dim3(16 * 5 * 2 * 23), dim3(CTHREADS), 0, stream, A0, BV, K1R, P1);
    hipLaunchKernelGGL((combine_gate_kernel<5>), dim3((16 * 5832 + THREADS - 1) / THREADS),
                       dim3(THREADS), 0, stream, P1, A1);
    hipLaunchKernelGGL((conv_kernel<20, 2, 20, 20, 18, 10, 20, 10, 2, 3, 0>),
                       dim3(16 * 10 * 2 * 4), dim3(CTHREADS), 0, stream, A1, BV, K2R, P2);
    hipLaunchKernelGGL(head_kernel<10>, dim3(BATCH), dim3(THREADS), 0, stream, P2, fc1w, fc1b,
                       fc2w, fc2b, out);
  } else if (favail >= fixed + (size_t)4 * BATCH * 23 * 5832) {
    // Tier B (proven fit, 92.8 MB): G=4 (ICG=5), och-split x2 -> 2944 blocks.
    hipLaunchKernelGGL((conv_kernel<20, 5, 23, 24, 33, 18, 36, 18, 2, 3, 0>),
                       dim3(16 * 4 * 2 * 23), dim3(CTHREADS), 0, stream, A0, BV, K1R, P1);
    hipLaunchKernelGGL((combine_gate_kernel<4>), dim3((16 * 5832 + THREADS - 1) / THREADS),
                       dim3(THREADS), 0, stream, P1, A1);
    hipLaunchKernelGGL((conv_kernel<20, 2, 20, 20, 18, 10, 20, 10, 2, 3, 0>),
                       dim3(16 * 10 * 2 * 4), dim3(CTHREADS), 0, stream, A1, BV, K2R, P2);
    hipLaunchKernelGGL(head_kernel<10>, dim3(BATCH), dim3(THREADS), 0, stream, P2, fc1w, fc1b,
                       fc2w, fc2b, out);
  } else if (favail >= fixed + (size_t)2 * BATCH * 23 * 5832) {
    // Tier C: G=2 (ICG=10), och-split x2 -> 1472 blocks.
    hipLaunchKernelGGL((conv_kernel<20, 10, 23, 24, 33, 18, 36, 18, 2, 3, 0>),
                       dim3(16 * 2 * 2 * 23), dim3(CTHREADS), 0, stream, A0, BV, K1R, P1);
    hipLaunchKernelGGL((combine_gate_kernel<2>), dim3((16 * 5832 + THREADS - 1) / THREADS),
                       dim3(THREADS), 0, stream, P1, A1);
    hipLaunchKernelGGL((conv_kernel<20, 2, 20, 20, 18, 10, 20, 10, 2, 3, 0>),
                       dim3(16 * 10 * 2 * 4), dim3(CTHREADS), 0, stream, A1, BV, K2R, P2);
    hipLaunchKernelGGL(head_kernel<10>, dim3(BATCH), dim3(THREADS), 0, stream, P2, fc1w, fc1b,
                       fc2w, fc2b, out);
  } else {
    // Tier D: fused fallback. conv1 writes A1 padded directly (gated), conv2 plain.
    float* A2 = P1;
    hipLaunchKernelGGL((conv_kernel<20, 20, 23, 24, 33, 18, 36, 20, 1, 6, 1>), dim3(16 * 23),
                       dim3(CTHREADS), 0, stream, A0, BV, K1R, A1);
    hipLaunchKernelGGL((conv_kernel<20, 20, 20, 20, 18, 10, 20, 10, 1, 5, 2>), dim3(16 * 4),
                       dim3(CTHREADS), 0, stream, A1, BV, K2R, A2);
    hipLaunchKernelGGL(head_kernel<1>, dim3(BATCH), dim3(THREADS), 0, stream, A2, fc1w, fc1b,
                       fc2w, fc2b, out);
  }
}

// Round 8
// 218.834 us; speedup vs baseline: 29.6680x; 1.2067x over previous
//
#include <hip/hip_runtime.h>
#include <math.h>
#include <type_traits>

#define CTHREADS 128   // conv kernels
#define THREADS 256    // aux kernels
constexpr int BATCH = 16;

// ---------------------------------------------------------------------------
// Radial reduction + vectorized loads + (round 8) XCD-pinned swizzle and
// 2-bank software pipeline over kz-planes.
//
// Workspace (floats):
//   BV 40 | K0R 72 | K1R 1440 | K2R 1200 | XM 320
//   A0 [16][20][33][33][36] : 12,545,280   (rows padded 33->36)
//   A1 [16][20][18][18][20] :  2,073,600   (rows padded 18->20)
//   P1 [G1][16][23][5832]   (tier B G1=4: 8,584,704)
//   P2 [10][16][20][1000] aliases A0.
// ---------------------------------------------------------------------------

__host__ __device__ constexpr int QI(int q) {  // q = ay^2+ax^2 in {0,1,2,4,5,8}
  return q == 0 ? 0 : q == 1 ? 1 : q == 2 ? 2 : q == 4 ? 3 : q == 5 ? 4 : 5;
}

__global__ void synth_kernel(const float* __restrict__ W0,
                             const float* __restrict__ W1,
                             const float* __restrict__ W2,
                             float* __restrict__ BV,
                             float* __restrict__ K0R,
                             float* __restrict__ K1R,
                             float* __restrict__ K2R) {
  __shared__ float Bsh[3][128];
  __shared__ float nrm[3];
  const int t = threadIdx.x;
  if (t < 125) {
    float dz = (float)(t / 25) - 2.0f;
    float dy = (float)((t / 5) % 5) - 2.0f;
    float dx = (float)(t % 5) - 2.0f;
    float r = sqrtf(dx * dx + dy * dy + dz * dz);
    for (int j = 0; j < 3; ++j) {
      float d = (r - (float)j) * (1.0f / 0.6f);
      Bsh[j][t] = expf(-0.5f * d * d);
    }
  }
  __syncthreads();
  if (t < 3) {
    float s = 0.f;
    for (int k = 0; k < 125; ++k) s += Bsh[t][k] * Bsh[t][k];
    nrm[t] = rsqrtf(s);
  }
  __syncthreads();
  if (t < 40) {
    const int g = t / 4, j = t % 4;
    constexpr int R2C[10] = {0, 1, 2, 3, 4, 5, 6, 8, 9, 12};
    if (j < 3) {
      float d = (sqrtf((float)R2C[g]) - (float)j) * (1.0f / 0.6f);
      BV[t] = expf(-0.5f * d * d) * nrm[j];
    } else {
      BV[t] = 0.f;
    }
  }
  for (int i = t; i < 3 * 24; i += blockDim.x) {
    int j = i / 24, oc = i % 24;
    K0R[i] = (oc < 23) ? W0[oc * 3 + j] : 0.f;
  }
  for (int i = t; i < 20 * 3 * 24; i += blockDim.x) {
    int oc = i % 24, j = (i / 24) % 3, ic = i / 72;
    K1R[i] = (oc < 23) ? W1[(oc * 20 + ic) * 3 + j] : 0.f;
  }
  for (int i = t; i < 20 * 3 * 20; i += blockDim.x) {
    int oc = i % 20, j = (i / 20) % 3, ic = i / 60;
    K2R[i] = W2[(oc * 20 + ic) * 3 + j];
  }
}

// Direct conv via radial classes. Thread = 2 x-consecutive voxels; block picks
// an oc-chunk (och). Block index is XCD-pinned: bid%8 = xcd, b = xcd+8*bh, och
// pair 8 apart in dispatch -> same XCD L2 serves both. kz-planes are processed
// through a 2-bank register pipeline (named banks, static 10-stage sequence) so
// the next plane's 10 float4 loads are in flight during current plane's VALU.
// EPI: 0 = partials [g][b][OC][vox] packed, 1 = gated 20ch, 2 = plain.
template <int ICTOT, int ICG, int OC, int OCP, int DIN, int DOUT, int IRS, int ORS,
          int OCB, int C4N, int EPI>
__global__ __launch_bounds__(CTHREADS)
void conv_kernel(const float* __restrict__ in, const float* __restrict__ BV,
                 const float* __restrict__ KR, float* __restrict__ out) {
  constexpr int G = ICTOT / ICG;
  constexpr int ISLAB = DIN * DIN * IRS;
  constexpr int OSLAB = DOUT * DOUT * ORS;
  constexpr int XS = (DOUT + 1) / 2;
  constexpr int SPI = DOUT * DOUT * XS;
  constexpr int NB = (SPI + CTHREADS - 1) / CTHREADS;
  constexpr int CW = C4N * 4;

  __shared__ __align__(16) float lbv[40];
  __shared__ __align__(16) float lw[ICG * 3 * CW];

  // XCD-pinned decode (grid = 8 * (2*G*OCB*NB), BATCH=16)
  const int bid = blockIdx.x;
  const int xcd = bid & 7;
  int slot = bid >> 3;
  const int och = slot % OCB;
  slot /= OCB;
  const int chunk = slot % NB;
  slot /= NB;
  const int g = slot % G;
  const int bh = slot / G;
  const int b = xcd + 8 * bh;
  const int c4lo = och * C4N;
  const int t = threadIdx.x;

  for (int i = t; i < 40; i += CTHREADS) lbv[i] = BV[i];
  for (int i = t; i < ICG * 3 * CW; i += CTHREADS) {
    const int cc = i % CW;
    const int jj = (i / CW) % 3;
    const int icl = i / (3 * CW);
    const int col = c4lo * 4 + cc;
    lw[i] = (col < OCP) ? KR[((size_t)(g * ICG + icl) * 3 + jj) * OCP + col] : 0.f;
  }
  __syncthreads();

  const int s = chunk * CTHREADS + t;
  const bool active = s < SPI;
  const int si = active ? s : 0;
  const int zo = si / (DOUT * XS);
  const int yo = (si / XS) % DOUT;
  const int xo0 = (si % XS) * 2;

  float acc[CW][2];
#pragma unroll
  for (int c = 0; c < CW; ++c) {
    acc[c][0] = 0.f;
    acc[c][1] = 0.f;
  }

  const float* __restrict__ ip0 = in + (size_t)(b * ICTOT + g * ICG) * ISLAB;
  const int offA = max(2 * xo0 - 4, 0);
  const int offB = min(2 * xo0, IRS - 4);
  bool xok[7];
#pragma unroll
  for (int p = 0; p < 7; ++p) xok[p] = (unsigned)(2 * xo0 - 3 + p) < (unsigned)DIN;
  int yoff[5];
  bool yok[5];
#pragma unroll
  for (int ky = 0; ky < 5; ++ky) {
    const int yi = 2 * yo - 3 + ky;
    yok[ky] = (unsigned)yi < (unsigned)DIN;
    yoff[ky] = min(max(yi, 0), DIN - 1) * IRS;
  }

#pragma unroll 1
  for (int icl = 0; icl < ICG; ++icl) {
    const float* __restrict__ ipc = ip0 + (size_t)icl * ISLAB;
    float sg[10][2];
#pragma unroll
    for (int gg = 0; gg < 10; ++gg) {
      sg[gg][0] = 0.f;
      sg[gg][1] = 0.f;
    }

    float4 Aa[5], Ab[5], Ba[5], Bb[5];
    bool zokA, zokB;

    auto LOADA = [&](int kz) {
      const int zi = 2 * zo - 3 + kz;
      zokA = (unsigned)zi < (unsigned)DIN;
      const float* pl = ipc + (size_t)min(max(zi, 0), DIN - 1) * (DIN * IRS);
#pragma unroll
      for (int ky = 0; ky < 5; ++ky) {
        const float* row = pl + yoff[ky];
        Aa[ky] = *(const float4*)(row + offA);
        Ab[ky] = *(const float4*)(row + offB);
      }
    };
    auto LOADBK = [&](int kz) {
      const int zi = 2 * zo - 3 + kz;
      zokB = (unsigned)zi < (unsigned)DIN;
      const float* pl = ipc + (size_t)min(max(zi, 0), DIN - 1) * (DIN * IRS);
#pragma unroll
      for (int ky = 0; ky < 5; ++ky) {
        const float* row = pl + yoff[ky];
        Ba[ky] = *(const float4*)(row + offA);
        Bb[ky] = *(const float4*)(row + offB);
      }
    };
    auto PROC = [&](auto azc_c, float4 (&pa)[5], float4 (&pb)[5], bool zk) {
      constexpr int AZC = decltype(azc_c)::value;
      constexpr int GM[3][6] = {
          {0, 1, 2, 4, 5, 7}, {1, 2, 3, 5, 6, 8}, {4, 5, 6, 7, 8, 9}};
      constexpr int A2[5] = {4, 1, 0, 1, 4};
      float pq[6][2];
#pragma unroll
      for (int qi = 0; qi < 6; ++qi) {
        pq[qi][0] = 0.f;
        pq[qi][1] = 0.f;
      }
#pragma unroll
      for (int ky = 0; ky < 5; ++ky) {
        float v[7] = {pa[ky].y, pa[ky].z, pa[ky].w, pb[ky].x, pb[ky].y, pb[ky].z, pb[ky].w};
        const bool yz = zk && yok[ky];
#pragma unroll
        for (int p = 0; p < 7; ++p) v[p] = (yz && xok[p]) ? v[p] : 0.f;
#pragma unroll
        for (int kx = 0; kx < 5; ++kx) {
          pq[QI(A2[ky] + A2[kx])][0] += v[kx];
          pq[QI(A2[ky] + A2[kx])][1] += v[2 + kx];
        }
      }
#pragma unroll
      for (int qi = 0; qi < 6; ++qi) {
        sg[GM[AZC][qi]][0] += pq[qi][0];
        sg[GM[AZC][qi]][1] += pq[qi][1];
      }
    };

    // kz sequence with az^2-class: 2->0, 1->1, 3->1, 0->2, 4->2
    LOADA(2);
    LOADBK(1);
    PROC(std::integral_constant<int, 0>{}, Aa, Ab, zokA);
    LOADA(3);
    PROC(std::integral_constant<int, 1>{}, Ba, Bb, zokB);
    LOADBK(0);
    PROC(std::integral_constant<int, 1>{}, Aa, Ab, zokA);
    LOADA(4);
    PROC(std::integral_constant<int, 2>{}, Ba, Bb, zokB);
    PROC(std::integral_constant<int, 2>{}, Aa, Ab, zokA);

    float z[3][2];
#pragma unroll
    for (int j = 0; j < 3; ++j) {
      z[j][0] = 0.f;
      z[j][1] = 0.f;
    }
#pragma unroll
    for (int gg = 0; gg < 10; ++gg) {
      const float4 bv4 = *(const float4*)&lbv[gg * 4];
#pragma unroll
      for (int n = 0; n < 2; ++n) {
        z[0][n] = fmaf(bv4.x, sg[gg][n], z[0][n]);
        z[1][n] = fmaf(bv4.y, sg[gg][n], z[1][n]);
        z[2][n] = fmaf(bv4.z, sg[gg][n], z[2][n]);
      }
    }
#pragma unroll
    for (int j = 0; j < 3; ++j) {
#pragma unroll
      for (int c4 = 0; c4 < C4N; ++c4) {
        const float4 w4 = *(const float4*)&lw[(icl * 3 + j) * CW + 4 * c4];
#pragma unroll
        for (int n = 0; n < 2; ++n) {
          acc[c4 * 4 + 0][n] = fmaf(w4.x, z[j][n], acc[c4 * 4 + 0][n]);
          acc[c4 * 4 + 1][n] = fmaf(w4.y, z[j][n], acc[c4 * 4 + 1][n]);
          acc[c4 * 4 + 2][n] = fmaf(w4.z, z[j][n], acc[c4 * 4 + 2][n]);
          acc[c4 * 4 + 3][n] = fmaf(w4.w, z[j][n], acc[c4 * 4 + 3][n]);
        }
      }
    }
  }

  if (!active) return;
  const int vbase = (zo * DOUT + yo) * ORS + xo0;

  if constexpr (EPI == 1) {
    float* __restrict__ op = out + (size_t)b * 20 * OSLAB + vbase;
#pragma unroll
    for (int n = 0; n < 2; ++n) {
      if (xo0 + n < DOUT) {
        const float g0 = 1.f / (1.f + expf(-acc[20][n]));
        const float g1 = 1.f / (1.f + expf(-acc[21][n]));
        const float g2 = 1.f / (1.f + expf(-acc[22][n]));
#pragma unroll
        for (int c = 0; c < 5; ++c) op[(size_t)c * OSLAB + n] = fmaxf(acc[c][n], 0.f);
#pragma unroll
        for (int c = 0; c < 3; ++c) op[(size_t)(5 + c) * OSLAB + n] = acc[5 + c][n] * g0;
#pragma unroll
        for (int c = 0; c < 5; ++c) op[(size_t)(8 + c) * OSLAB + n] = acc[8 + c][n] * g1;
#pragma unroll
        for (int c = 0; c < 7; ++c) op[(size_t)(13 + c) * OSLAB + n] = acc[13 + c][n] * g2;
      }
    }
  } else if constexpr (EPI == 0) {
    float* __restrict__ op = out + ((size_t)(g * BATCH + b) * OC) * OSLAB + vbase;
#pragma unroll
    for (int c = 0; c < CW; ++c) {
      const int oc = c4lo * 4 + c;
      if (oc < OC) {
#pragma unroll
        for (int n = 0; n < 2; ++n)
          if (xo0 + n < DOUT) op[(size_t)oc * OSLAB + n] = acc[c][n];
      }
    }
  } else {
    float* __restrict__ op = out + (size_t)b * OC * OSLAB + vbase;
#pragma unroll
    for (int c = 0; c < CW; ++c) {
      const int oc = c4lo * 4 + c;
      if (oc < OC) {
#pragma unroll
        for (int n = 0; n < 2; ++n)
          if (xo0 + n < DOUT) op[(size_t)oc * OSLAB + n] = acc[c][n];
      }
    }
  }
}

// Sum ic-group partials (23 ch, packed) + gating -> A1 padded (row stride 20).
template <int G>
__global__ __launch_bounds__(THREADS)
void combine_gate_kernel(const float* __restrict__ P, float* __restrict__ out) {
  const int tid = blockIdx.x * THREADS + threadIdx.x;
  if (tid >= BATCH * 5832) return;
  const int vox = tid % 5832;
  const int b = tid / 5832;
  float s[23];
#pragma unroll
  for (int oc = 0; oc < 23; ++oc) s[oc] = 0.f;
  for (int g = 0; g < G; ++g) {
    const float* __restrict__ p = P + ((size_t)(g * BATCH + b) * 23) * 5832 + vox;
#pragma unroll
    for (int oc = 0; oc < 23; ++oc) s[oc] += p[(size_t)oc * 5832];
  }
  const float g0 = 1.f / (1.f + expf(-s[20]));
  const float g1 = 1.f / (1.f + expf(-s[21]));
  const float g2 = 1.f / (1.f + expf(-s[22]));
  const int zz = vox / 324, yy = (vox / 18) % 18, xx = vox % 18;
  float* __restrict__ op = out + (size_t)b * 20 * 6480 + (zz * 18 + yy) * 20 + xx;
#pragma unroll
  for (int c = 0; c < 5; ++c) op[(size_t)c * 6480] = fmaxf(s[c], 0.f);
#pragma unroll
  for (int c = 0; c < 3; ++c) op[(size_t)(5 + c) * 6480] = s[5 + c] * g0;
#pragma unroll
  for (int c = 0; c < 5; ++c) op[(size_t)(8 + c) * 6480] = s[8 + c] * g1;
#pragma unroll
  for (int c = 0; c < 7; ++c) op[(size_t)(13 + c) * 6480] = s[13 + c] * g2;
}

// AvgSpacial stage 1: one block per (b,ch), float4 loads, -> XM[b*20+ch].
template <int G>
__global__ __launch_bounds__(THREADS)
void reduce_kernel(const float* __restrict__ P2, float* __restrict__ XM) {
  const int b = blockIdx.x / 20, ch = blockIdx.x % 20;
  const int t = threadIdx.x;
  float s = 0.f;
  for (int i = t; i < G * 250; i += THREADS) {
    const int g = i / 250, v = i % 250;
    const float4 x = *(const float4*)(P2 + ((size_t)(g * BATCH + b) * 20 + ch) * 1000 + v * 4);
    s += x.x + x.y + x.z + x.w;
  }
  __shared__ float red[THREADS];
  red[t] = s;
  __syncthreads();
  for (int st = THREADS / 2; st > 0; st >>= 1) {
    if (t < st) red[t] += red[t + st];
    __syncthreads();
  }
  if (t == 0) XM[b * 20 + ch] = red[0] * (1.0f / 1000.0f);
}

// AvgSpacial stage 2: fc1(relu) + fc2 for all batches, one block.
__global__ __launch_bounds__(THREADS)
void fc_kernel(const float* __restrict__ XM,
               const float* __restrict__ fc1w, const float* __restrict__ fc1b,
               const float* __restrict__ fc2w, const float* __restrict__ fc2b,
               float* __restrict__ out) {
  const int t = threadIdx.x;
  __shared__ float xs[320];
  __shared__ float hh[800];
  for (int i = t; i < 320; i += THREADS) xs[i] = XM[i];
  __syncthreads();
  for (int i = t; i < 800; i += THREADS) {
    const int b = i / 50, j = i % 50;
    float s = fc1b[j];
    for (int c = 0; c < 20; ++c) s += xs[b * 20 + c] * fc1w[j * 20 + c];
    hh[i] = fmaxf(s, 0.f);
  }
  __syncthreads();
  for (int i = t; i < 32; i += THREADS) {
    const int b = i / 2, k = i % 2;
    float s = fc2b[k];
    for (int j = 0; j < 50; ++j) s += hh[b * 50 + j] * fc2w[k * 50 + j];
    out[b * 2 + k] = s;
  }
}

extern "C" void kernel_launch(void* const* d_in, const int* in_sizes, int n_in,
                              void* d_out, int out_size, void* d_ws, size_t ws_size,
                              hipStream_t stream) {
  (void)in_sizes; (void)n_in; (void)out_size;
  const float* inp  = (const float*)d_in[0];
  const float* W0   = (const float*)d_in[1];
  const float* W1   = (const float*)d_in[2];
  const float* W2   = (const float*)d_in[3];
  const float* fc1w = (const float*)d_in[4];
  const float* fc1b = (const float*)d_in[5];
  const float* fc2w = (const float*)d_in[6];
  const float* fc2b = (const float*)d_in[7];
  float* out = (float*)d_out;

  float* ws = (float*)d_ws;
  float* BV  = ws;                       // 40
  float* K0R = BV + 40;                  // 72
  float* K1R = K0R + 72;                 // 1440
  float* K2R = K1R + 1440;               // 1200
  float* XM  = K2R + 1200;               // 320
  float* A0  = XM + 320;                 // 12,545,280 (padded rows 36)
  float* A1  = A0 + (size_t)12545280;    // 2,073,600  (padded rows 20)
  float* P1  = A1 + (size_t)2073600;     // variable
  float* P2  = A0;                       // conv2 partials alias dead A0

  const size_t favail = ws_size / 4;
  const size_t fixed = 40 + 72 + 1440 + 1200 + 320 + (size_t)12545280 + 2073600;

  hipLaunchKernelGGL(synth_kernel, dim3(1), dim3(256), 0, stream, W0, W1, W2, BV, K0R, K1R, K2R);

  // conv0: SPI=18513, NB=145, grid 2320 (=8*290).
  hipLaunchKernelGGL((conv_kernel<1, 1, 23, 24, 64, 33, 64, 36, 1, 6, 1>), dim3(16 * 145),
                     dim3(CTHREADS), 0, stream, inp, BV, K0R, A0);

  if (favail >= fixed + (size_t)5 * BATCH * 23 * 5832) {
    // Tier A: conv1 G=5 (ICG=4), och x2, NB=23 -> 3680 blocks.
    hipLaunchKernelGGL((conv_kernel<20, 4, 23, 24, 33, 18, 36, 18, 2, 3, 0>),
                       dim3(16 * 5 * 2 * 23), dim3(CTHREADS), 0, stream, A0, BV, K1R, P1);
    hipLaunchKernelGGL((combine_gate_kernel<5>), dim3((16 * 5832 + THREADS - 1) / THREADS),
                       dim3(THREADS), 0, stream, P1, A1);
    hipLaunchKernelGGL((conv_kernel<20, 2, 20, 20, 18, 10, 20, 10, 2, 3, 0>),
                       dim3(16 * 10 * 2 * 4), dim3(CTHREADS), 0, stream, A1, BV, K2R, P2);
    hipLaunchKernelGGL(reduce_kernel<10>, dim3(320), dim3(THREADS), 0, stream, P2, XM);
    hipLaunchKernelGGL(fc_kernel, dim3(1), dim3(THREADS), 0, stream, XM, fc1w, fc1b, fc2w, fc2b,
                       out);
  } else if (favail >= fixed + (size_t)4 * BATCH * 23 * 5832) {
    // Tier B: conv1 G=4 (ICG=5) -> 2944 blocks.
    hipLaunchKernelGGL((conv_kernel<20, 5, 23, 24, 33, 18, 36, 18, 2, 3, 0>),
                       dim3(16 * 4 * 2 * 23), dim3(CTHREADS), 0, stream, A0, BV, K1R, P1);
    hipLaunchKernelGGL((combine_gate_kernel<4>), dim3((16 * 5832 + THREADS - 1) / THREADS),
                       dim3(THREADS), 0, stream, P1, A1);
    hipLaunchKernelGGL((conv_kernel<20, 2, 20, 20, 18, 10, 20, 10, 2, 3, 0>),
                       dim3(16 * 10 * 2 * 4), dim3(CTHREADS), 0, stream, A1, BV, K2R, P2);
    hipLaunchKernelGGL(reduce_kernel<10>, dim3(320), dim3(THREADS), 0, stream, P2, XM);
    hipLaunchKernelGGL(fc_kernel, dim3(1), dim3(THREADS), 0, stream, XM, fc1w, fc1b, fc2w, fc2b,
                       out);
  } else if (favail >= fixed + (size_t)2 * BATCH * 23 * 5832) {
    // Tier C: conv1 G=2 (ICG=10) -> 1472 blocks.
    hipLaunchKernelGGL((conv_kernel<20, 10, 23, 24, 33, 18, 36, 18, 2, 3, 0>),
                       dim3(16 * 2 * 2 * 23), dim3(CTHREADS), 0, stream, A0, BV, K1R, P1);
    hipLaunchKernelGGL((combine_gate_kernel<2>), dim3((16 * 5832 + THREADS - 1) / THREADS),
                       dim3(THREADS), 0, stream, P1, A1);
    hipLaunchKernelGGL((conv_kernel<20, 2, 20, 20, 18, 10, 20, 10, 2, 3, 0>),
                       dim3(16 * 10 * 2 * 4), dim3(CTHREADS), 0, stream, A1, BV, K2R, P2);
    hipLaunchKernelGGL(reduce_kernel<10>, dim3(320), dim3(THREADS), 0, stream, P2, XM);
    hipLaunchKernelGGL(fc_kernel, dim3(1), dim3(THREADS), 0, stream, XM, fc1w, fc1b, fc2w, fc2b,
                       out);
  } else {
    // Tier D: fused fallback. conv1 gated -> A1 padded, conv2 plain -> A2.
    float* A2 = P1;
    hipLaunchKernelGGL((conv_kernel<20, 20, 23, 24, 33, 18, 36, 20, 1, 6, 1>), dim3(16 * 23),
                       dim3(CTHREADS), 0, stream, A0, BV, K1R, A1);
    hipLaunchKernelGGL((conv_kernel<20, 20, 20, 20, 18, 10, 20, 10, 1, 5, 2>), dim3(16 * 4),
                       dim3(CTHREADS), 0, stream, A1, BV, K2R, A2);
    hipLaunchKernelGGL(reduce_kernel<1>, dim3(320), dim3(THREADS), 0, stream, A2, XM);
    hipLaunchKernelGGL(fc_kernel, dim3(1), dim3(THREADS), 0, stream, XM, fc1w, fc1b, fc2w, fc2b,
                       out);
  }
}

// Round 9
// 105.721 us; speedup vs baseline: 61.4100x; 2.0699x over previous
//
#include <hip/hip_runtime.h>
#include <math.h>
#include <type_traits>

#define CTHREADS 128   // conv kernels
#define THREADS 256    // aux kernels
constexpr int BATCH = 16;

// ---------------------------------------------------------------------------
// Radial reduction + vectorized loads + XCD-pinned swizzle (round 8) with the
// och-split and register pipeline removed (round 9): och duplicated the 125-tap
// radial sums per oc-chunk (2x VALU + 2x L2 reads), and the 2-bank pipeline's
// 80 VGPRs capped residency at 2 waves/SIMD. Full-width acc (C4N=6) + plane-
// local loads keeps VGPR ~115 -> 4 waves/SIMD; latency hidden by TLP.
//
// Workspace (floats):
//   BV 40 | K0R 72 | K1R 1440 | K2R 1200 | XM 320
//   A0 [16][20][33][33][36] : 12,545,280   (rows padded 33->36)
//   A1 [16][20][18][18][20] :  2,073,600   (rows padded 18->20)
//   P1 [G1][16][23][5832]   (tier A G1=5: 10,730,880)
//   P2 [20][16][20][1000] aliases A0 (6.4M < 12.5M).
// ---------------------------------------------------------------------------

__host__ __device__ constexpr int QI(int q) {  // q = ay^2+ax^2 in {0,1,2,4,5,8}
  return q == 0 ? 0 : q == 1 ? 1 : q == 2 ? 2 : q == 4 ? 3 : q == 5 ? 4 : 5;
}

__global__ void synth_kernel(const float* __restrict__ W0,
                             const float* __restrict__ W1,
                             const float* __restrict__ W2,
                             float* __restrict__ BV,
                             float* __restrict__ K0R,
                             float* __restrict__ K1R,
                             float* __restrict__ K2R) {
  __shared__ float Bsh[3][128];
  __shared__ float nrm[3];
  const int t = threadIdx.x;
  if (t < 125) {
    float dz = (float)(t / 25) - 2.0f;
    float dy = (float)((t / 5) % 5) - 2.0f;
    float dx = (float)(t % 5) - 2.0f;
    float r = sqrtf(dx * dx + dy * dy + dz * dz);
    for (int j = 0; j < 3; ++j) {
      float d = (r - (float)j) * (1.0f / 0.6f);
      Bsh[j][t] = expf(-0.5f * d * d);
    }
  }
  __syncthreads();
  if (t < 3) {
    float s = 0.f;
    for (int k = 0; k < 125; ++k) s += Bsh[t][k] * Bsh[t][k];
    nrm[t] = rsqrtf(s);
  }
  __syncthreads();
  if (t < 40) {
    const int g = t / 4, j = t % 4;
    constexpr int R2C[10] = {0, 1, 2, 3, 4, 5, 6, 8, 9, 12};
    if (j < 3) {
      float d = (sqrtf((float)R2C[g]) - (float)j) * (1.0f / 0.6f);
      BV[t] = expf(-0.5f * d * d) * nrm[j];
    } else {
      BV[t] = 0.f;
    }
  }
  for (int i = t; i < 3 * 24; i += blockDim.x) {
    int j = i / 24, oc = i % 24;
    K0R[i] = (oc < 23) ? W0[oc * 3 + j] : 0.f;
  }
  for (int i = t; i < 20 * 3 * 24; i += blockDim.x) {
    int oc = i % 24, j = (i / 24) % 3, ic = i / 72;
    K1R[i] = (oc < 23) ? W1[(oc * 20 + ic) * 3 + j] : 0.f;
  }
  for (int i = t; i < 20 * 3 * 20; i += blockDim.x) {
    int oc = i % 20, j = (i / 20) % 3, ic = i / 60;
    K2R[i] = W2[(oc * 20 + ic) * 3 + j];
  }
}

// Direct conv via radial classes. Thread = 2 x-consecutive voxels, ALL OC
// channels of one ic-group. Block index XCD-pinned: bid&7 = xcd, b = xcd+8*bh.
// Plane loads are lambda-local (10 float4 in flight only within a plane) ->
// bounded liveness without sched_barriers (round 3-5 lesson) and no persistent
// pipeline banks (round 8 lesson).
// EPI: 0 = partials [g][b][OC][vox] packed, 1 = gated 20ch, 2 = plain.
template <int ICTOT, int ICG, int OC, int OCP, int DIN, int DOUT, int IRS, int ORS,
          int C4N, int EPI>
__global__ __launch_bounds__(CTHREADS)
void conv_kernel(const float* __restrict__ in, const float* __restrict__ BV,
                 const float* __restrict__ KR, float* __restrict__ out) {
  constexpr int G = ICTOT / ICG;
  constexpr int ISLAB = DIN * DIN * IRS;
  constexpr int OSLAB = DOUT * DOUT * ORS;
  constexpr int XS = (DOUT + 1) / 2;
  constexpr int SPI = DOUT * DOUT * XS;
  constexpr int NB = (SPI + CTHREADS - 1) / CTHREADS;
  constexpr int CW = C4N * 4;
  static_assert(CW == OCP, "full-width acc");

  __shared__ __align__(16) float lbv[40];
  __shared__ __align__(16) float lw[ICG * 3 * CW];

  // XCD-pinned decode (grid = 8 * NB * G * (BATCH/8))
  const int bid = blockIdx.x;
  const int xcd = bid & 7;
  int slot = bid >> 3;
  const int chunk = slot % NB;
  slot /= NB;
  const int g = slot % G;
  const int bh = slot / G;
  const int b = xcd + 8 * bh;
  const int t = threadIdx.x;

  for (int i = t; i < 40; i += CTHREADS) lbv[i] = BV[i];
  for (int i = t; i < ICG * 3 * CW; i += CTHREADS)
    lw[i] = KR[(size_t)g * ICG * 3 * OCP + i];
  __syncthreads();

  const int s = chunk * CTHREADS + t;
  const bool active = s < SPI;
  const int si = active ? s : 0;
  const int zo = si / (DOUT * XS);
  const int yo = (si / XS) % DOUT;
  const int xo0 = (si % XS) * 2;

  float acc[CW][2];
#pragma unroll
  for (int c = 0; c < CW; ++c) {
    acc[c][0] = 0.f;
    acc[c][1] = 0.f;
  }

  const float* __restrict__ ip0 = in + (size_t)(b * ICTOT + g * ICG) * ISLAB;
  const int offA = max(2 * xo0 - 4, 0);
  const int offB = min(2 * xo0, IRS - 4);
  bool xok[7];
#pragma unroll
  for (int p = 0; p < 7; ++p) xok[p] = (unsigned)(2 * xo0 - 3 + p) < (unsigned)DIN;
  int yoff[5];
  bool yok[5];
#pragma unroll
  for (int ky = 0; ky < 5; ++ky) {
    const int yi = 2 * yo - 3 + ky;
    yok[ky] = (unsigned)yi < (unsigned)DIN;
    yoff[ky] = min(max(yi, 0), DIN - 1) * IRS;
  }

#pragma unroll 1
  for (int icl = 0; icl < ICG; ++icl) {
    const float* __restrict__ ipc = ip0 + (size_t)icl * ISLAB;
    float sg[10][2];
#pragma unroll
    for (int gg = 0; gg < 10; ++gg) {
      sg[gg][0] = 0.f;
      sg[gg][1] = 0.f;
    }

    auto plane = [&](auto azc_c, int kz) {
      constexpr int AZC = decltype(azc_c)::value;
      constexpr int GM[3][6] = {
          {0, 1, 2, 4, 5, 7}, {1, 2, 3, 5, 6, 8}, {4, 5, 6, 7, 8, 9}};
      constexpr int A2[5] = {4, 1, 0, 1, 4};
      const int zi = 2 * zo - 3 + kz;
      const bool zok = (unsigned)zi < (unsigned)DIN;
      const float* pl = ipc + (size_t)min(max(zi, 0), DIN - 1) * (DIN * IRS);
      float4 pa[5], pb[5];
#pragma unroll
      for (int ky = 0; ky < 5; ++ky) {
        const float* row = pl + yoff[ky];
        pa[ky] = *(const float4*)(row + offA);
        pb[ky] = *(const float4*)(row + offB);
      }
      float pq[6][2];
#pragma unroll
      for (int qi = 0; qi < 6; ++qi) {
        pq[qi][0] = 0.f;
        pq[qi][1] = 0.f;
      }
#pragma unroll
      for (int ky = 0; ky < 5; ++ky) {
        float v[7] = {pa[ky].y, pa[ky].z, pa[ky].w, pb[ky].x, pb[ky].y, pb[ky].z, pb[ky].w};
        const bool yz = zok && yok[ky];
#pragma unroll
        for (int p = 0; p < 7; ++p) v[p] = (yz && xok[p]) ? v[p] : 0.f;
#pragma unroll
        for (int kx = 0; kx < 5; ++kx) {
          pq[QI(A2[ky] + A2[kx])][0] += v[kx];
          pq[QI(A2[ky] + A2[kx])][1] += v[2 + kx];
        }
      }
#pragma unroll
      for (int qi = 0; qi < 6; ++qi) {
        sg[GM[AZC][qi]][0] += pq[qi][0];
        sg[GM[AZC][qi]][1] += pq[qi][1];
      }
    };

    plane(std::integral_constant<int, 0>{}, 2);
#pragma unroll 1
    for (int rep = 0; rep < 2; ++rep) plane(std::integral_constant<int, 1>{}, 1 + 2 * rep);
#pragma unroll 1
    for (int rep = 0; rep < 2; ++rep) plane(std::integral_constant<int, 2>{}, 4 * rep);

    float z[3][2];
#pragma unroll
    for (int j = 0; j < 3; ++j) {
      z[j][0] = 0.f;
      z[j][1] = 0.f;
    }
#pragma unroll
    for (int gg = 0; gg < 10; ++gg) {
      const float4 bv4 = *(const float4*)&lbv[gg * 4];
#pragma unroll
      for (int n = 0; n < 2; ++n) {
        z[0][n] = fmaf(bv4.x, sg[gg][n], z[0][n]);
        z[1][n] = fmaf(bv4.y, sg[gg][n], z[1][n]);
        z[2][n] = fmaf(bv4.z, sg[gg][n], z[2][n]);
      }
    }
#pragma unroll
    for (int j = 0; j < 3; ++j) {
#pragma unroll
      for (int c4 = 0; c4 < C4N; ++c4) {
        const float4 w4 = *(const float4*)&lw[(icl * 3 + j) * CW + 4 * c4];
#pragma unroll
        for (int n = 0; n < 2; ++n) {
          acc[c4 * 4 + 0][n] = fmaf(w4.x, z[j][n], acc[c4 * 4 + 0][n]);
          acc[c4 * 4 + 1][n] = fmaf(w4.y, z[j][n], acc[c4 * 4 + 1][n]);
          acc[c4 * 4 + 2][n] = fmaf(w4.z, z[j][n], acc[c4 * 4 + 2][n]);
          acc[c4 * 4 + 3][n] = fmaf(w4.w, z[j][n], acc[c4 * 4 + 3][n]);
        }
      }
    }
  }

  if (!active) return;
  const int vbase = (zo * DOUT + yo) * ORS + xo0;

  if constexpr (EPI == 1) {
    float* __restrict__ op = out + (size_t)b * 20 * OSLAB + vbase;
#pragma unroll
    for (int n = 0; n < 2; ++n) {
      if (xo0 + n < DOUT) {
        const float g0 = 1.f / (1.f + expf(-acc[20][n]));
        const float g1 = 1.f / (1.f + expf(-acc[21][n]));
        const float g2 = 1.f / (1.f + expf(-acc[22][n]));
#pragma unroll
        for (int c = 0; c < 5; ++c) op[(size_t)c * OSLAB + n] = fmaxf(acc[c][n], 0.f);
#pragma unroll
        for (int c = 0; c < 3; ++c) op[(size_t)(5 + c) * OSLAB + n] = acc[5 + c][n] * g0;
#pragma unroll
        for (int c = 0; c < 5; ++c) op[(size_t)(8 + c) * OSLAB + n] = acc[8 + c][n] * g1;
#pragma unroll
        for (int c = 0; c < 7; ++c) op[(size_t)(13 + c) * OSLAB + n] = acc[13 + c][n] * g2;
      }
    }
  } else if constexpr (EPI == 0) {
    float* __restrict__ op = out + ((size_t)(g * BATCH + b) * OC) * OSLAB + vbase;
#pragma unroll
    for (int c = 0; c < CW; ++c) {
      if (c < OC) {
#pragma unroll
        for (int n = 0; n < 2; ++n)
          if (xo0 + n < DOUT) op[(size_t)c * OSLAB + n] = acc[c][n];
      }
    }
  } else {
    float* __restrict__ op = out + (size_t)b * OC * OSLAB + vbase;
#pragma unroll
    for (int c = 0; c < CW; ++c) {
      if (c < OC) {
#pragma unroll
        for (int n = 0; n < 2; ++n)
          if (xo0 + n < DOUT) op[(size_t)c * OSLAB + n] = acc[c][n];
      }
    }
  }
}

// Sum ic-group partials (23 ch, packed) + gating -> A1 padded (row stride 20).
template <int G>
__global__ __launch_bounds__(THREADS)
void combine_gate_kernel(const float* __restrict__ P, float* __restrict__ out) {
  const int tid = blockIdx.x * THREADS + threadIdx.x;
  if (tid >= BATCH * 5832) return;
  const int vox = tid % 5832;
  const int b = tid / 5832;
  float s[23];
#pragma unroll
  for (int oc = 0; oc < 23; ++oc) s[oc] = 0.f;
  for (int g = 0; g < G; ++g) {
    const float* __restrict__ p = P + ((size_t)(g * BATCH + b) * 23) * 5832 + vox;
#pragma unroll
    for (int oc = 0; oc < 23; ++oc) s[oc] += p[(size_t)oc * 5832];
  }
  const float g0 = 1.f / (1.f + expf(-s[20]));
  const float g1 = 1.f / (1.f + expf(-s[21]));
  const float g2 = 1.f / (1.f + expf(-s[22]));
  const int zz = vox / 324, yy = (vox / 18) % 18, xx = vox % 18;
  float* __restrict__ op = out + (size_t)b * 20 * 6480 + (zz * 18 + yy) * 20 + xx;
#pragma unroll
  for (int c = 0; c < 5; ++c) op[(size_t)c * 6480] = fmaxf(s[c], 0.f);
#pragma unroll
  for (int c = 0; c < 3; ++c) op[(size_t)(5 + c) * 6480] = s[5 + c] * g0;
#pragma unroll
  for (int c = 0; c < 5; ++c) op[(size_t)(8 + c) * 6480] = s[8 + c] * g1;
#pragma unroll
  for (int c = 0; c < 7; ++c) op[(size_t)(13 + c) * 6480] = s[13 + c] * g2;
}

// AvgSpacial stage 1: one block per (b,ch), float4 loads, -> XM[b*20+ch].
template <int G>
__global__ __launch_bounds__(THREADS)
void reduce_kernel(const float* __restrict__ P2, float* __restrict__ XM) {
  const int b = blockIdx.x / 20, ch = blockIdx.x % 20;
  const int t = threadIdx.x;
  float s = 0.f;
  for (int i = t; i < G * 250; i += THREADS) {
    const int g = i / 250, v = i % 250;
    const float4 x = *(const float4*)(P2 + ((size_t)(g * BATCH + b) * 20 + ch) * 1000 + v * 4);
    s += x.x + x.y + x.z + x.w;
  }
  __shared__ float red[THREADS];
  red[t] = s;
  __syncthreads();
  for (int st = THREADS / 2; st > 0; st >>= 1) {
    if (t < st) red[t] += red[t + st];
    __syncthreads();
  }
  if (t == 0) XM[b * 20 + ch] = red[0] * (1.0f / 1000.0f);
}

// AvgSpacial stage 2: fc1(relu) + fc2 for all batches, one block.
__global__ __launch_bounds__(THREADS)
void fc_kernel(const float* __restrict__ XM,
               const float* __restrict__ fc1w, const float* __restrict__ fc1b,
               const float* __restrict__ fc2w, const float* __restrict__ fc2b,
               float* __restrict__ out) {
  const int t = threadIdx.x;
  __shared__ float xs[320];
  __shared__ float hh[800];
  for (int i = t; i < 320; i += THREADS) xs[i] = XM[i];
  __syncthreads();
  for (int i = t; i < 800; i += THREADS) {
    const int b = i / 50, j = i % 50;
    float s = fc1b[j];
    for (int c = 0; c < 20; ++c) s += xs[b * 20 + c] * fc1w[j * 20 + c];
    hh[i] = fmaxf(s, 0.f);
  }
  __syncthreads();
  for (int i = t; i < 32; i += THREADS) {
    const int b = i / 2, k = i % 2;
    float s = fc2b[k];
    for (int j = 0; j < 50; ++j) s += hh[b * 50 + j] * fc2w[k * 50 + j];
    out[b * 2 + k] = s;
  }
}

extern "C" void kernel_launch(void* const* d_in, const int* in_sizes, int n_in,
                              void* d_out, int out_size, void* d_ws, size_t ws_size,
                              hipStream_t stream) {
  (void)in_sizes; (void)n_in; (void)out_size;
  const float* inp  = (const float*)d_in[0];
  const float* W0   = (const float*)d_in[1];
  const float* W1   = (const float*)d_in[2];
  const float* W2   = (const float*)d_in[3];
  const float* fc1w = (const float*)d_in[4];
  const float* fc1b = (const float*)d_in[5];
  const float* fc2w = (const float*)d_in[6];
  const float* fc2b = (const float*)d_in[7];
  float* out = (float*)d_out;

  float* ws = (float*)d_ws;
  float* BV  = ws;                       // 40
  float* K0R = BV + 40;                  // 72
  float* K1R = K0R + 72;                 // 1440
  float* K2R = K1R + 1440;               // 1200
  float* XM  = K2R + 1200;               // 320
  float* A0  = XM + 320;                 // 12,545,280 (padded rows 36)
  float* A1  = A0 + (size_t)12545280;    // 2,073,600  (padded rows 20)
  float* P1  = A1 + (size_t)2073600;     // variable
  float* P2  = A0;                       // conv2 partials alias dead A0

  const size_t favail = ws_size / 4;
  const size_t fixed = 40 + 72 + 1440 + 1200 + 320 + (size_t)12545280 + 2073600;

  hipLaunchKernelGGL(synth_kernel, dim3(1), dim3(256), 0, stream, W0, W1, W2, BV, K0R, K1R, K2R);

  // conv0: SPI=18513, NB=145, grid 8*145*1*2 = 2320.
  hipLaunchKernelGGL((conv_kernel<1, 1, 23, 24, 64, 33, 64, 36, 6, 1>), dim3(2320),
                     dim3(CTHREADS), 0, stream, inp, BV, K0R, A0);

  if (favail >= fixed + (size_t)5 * BATCH * 23 * 5832) {
    // Tier A: conv1 G=5 (ICG=4), NB=23 -> grid 8*23*5*2 = 1840.
    hipLaunchKernelGGL((conv_kernel<20, 4, 23, 24, 33, 18, 36, 18, 6, 0>), dim3(1840),
                       dim3(CTHREADS), 0, stream, A0, BV, K1R, P1);
    hipLaunchKernelGGL((combine_gate_kernel<5>), dim3((16 * 5832 + THREADS - 1) / THREADS),
                       dim3(THREADS), 0, stream, P1, A1);
    // conv2: ICG=1 x G=20, NB=4 -> grid 8*4*20*2 = 1280.
    hipLaunchKernelGGL((conv_kernel<20, 1, 20, 20, 18, 10, 20, 10, 5, 0>), dim3(1280),
                       dim3(CTHREADS), 0, stream, A1, BV, K2R, P2);
    hipLaunchKernelGGL(reduce_kernel<20>, dim3(320), dim3(THREADS), 0, stream, P2, XM);
    hipLaunchKernelGGL(fc_kernel, dim3(1), dim3(THREADS), 0, stream, XM, fc1w, fc1b, fc2w, fc2b,
                       out);
  } else if (favail >= fixed + (size_t)4 * BATCH * 23 * 5832) {
    // Tier B: conv1 G=4 (ICG=5) -> grid 8*23*4*2 = 1472.
    hipLaunchKernelGGL((conv_kernel<20, 5, 23, 24, 33, 18, 36, 18, 6, 0>), dim3(1472),
                       dim3(CTHREADS), 0, stream, A0, BV, K1R, P1);
    hipLaunchKernelGGL((combine_gate_kernel<4>), dim3((16 * 5832 + THREADS - 1) / THREADS),
                       dim3(THREADS), 0, stream, P1, A1);
    hipLaunchKernelGGL((conv_kernel<20, 1, 20, 20, 18, 10, 20, 10, 5, 0>), dim3(1280),
                       dim3(CTHREADS), 0, stream, A1, BV, K2R, P2);
    hipLaunchKernelGGL(reduce_kernel<20>, dim3(320), dim3(THREADS), 0, stream, P2, XM);
    hipLaunchKernelGGL(fc_kernel, dim3(1), dim3(THREADS), 0, stream, XM, fc1w, fc1b, fc2w, fc2b,
                       out);
  } else if (favail >= fixed + (size_t)2 * BATCH * 23 * 5832) {
    // Tier C: conv1 G=2 (ICG=10) -> grid 8*23*2*2 = 736.
    hipLaunchKernelGGL((conv_kernel<20, 10, 23, 24, 33, 18, 36, 18, 6, 0>), dim3(736),
                       dim3(CTHREADS), 0, stream, A0, BV, K1R, P1);
    hipLaunchKernelGGL((combine_gate_kernel<2>), dim3((16 * 5832 + THREADS - 1) / THREADS),
                       dim3(THREADS), 0, stream, P1, A1);
    hipLaunchKernelGGL((conv_kernel<20, 1, 20, 20, 18, 10, 20, 10, 5, 0>), dim3(1280),
                       dim3(CTHREADS), 0, stream, A1, BV, K2R, P2);
    hipLaunchKernelGGL(reduce_kernel<20>, dim3(320), dim3(THREADS), 0, stream, P2, XM);
    hipLaunchKernelGGL(fc_kernel, dim3(1), dim3(THREADS), 0, stream, XM, fc1w, fc1b, fc2w, fc2b,
                       out);
  } else {
    // Tier D: fused fallback. conv1 gated -> A1 padded, conv2 plain -> A2.
    float* A2 = P1;
    hipLaunchKernelGGL((conv_kernel<20, 20, 23, 24, 33, 18, 36, 20, 6, 1>), dim3(368),
                       dim3(CTHREADS), 0, stream, A0, BV, K1R, A1);
    hipLaunchKernelGGL((conv_kernel<20, 20, 20, 20, 18, 10, 20, 10, 5, 2>), dim3(128),
                       dim3(CTHREADS), 0, stream, A1, BV, K2R, A2);
    hipLaunchKernelGGL(reduce_kernel<1>, dim3(320), dim3(THREADS), 0, stream, A2, XM);
    hipLaunchKernelGGL(fc_kernel, dim3(1), dim3(THREADS), 0, stream, XM, fc1w, fc1b, fc2w, fc2b,
                       out);
  }
}